// Round 3
// baseline (102276.562 us; speedup 1.0000x reference)
//
#include <hip/hip_runtime.h>
#include <math.h>

#define B 128
#define H 256
#define V 130
#define L 100
#define G3 768
#define BH (B*H)
#define NWG 256
#define NT 512

// ---- workspace layout (4-byte words) ----
#define OFF_FLAGS 0               // 256 ints (grid barrier flags)
#define OFF_HID   256
#define OFF_Z1    (OFF_HID + BH)
#define OFF_Z2    (OFF_Z1 + 3*B*G3)
#define OFF_G1HA  (OFF_Z2 + 3*B*G3)
#define OFF_G1HB  (OFF_G1HA + 3*BH)
#define OFF_H2A   (OFF_G1HB + 3*BH)
#define OFF_H2B   (OFF_H2A + 3*BH)
#define OFF_CTXA  (OFF_H2B + 3*BH)
#define OFF_CTXB  (OFF_CTXA + BH)
#define OFF_U0    (OFF_CTXB + BH)
#define OFF_U1    (OFF_U0 + 3*BH)
#define OFF_NOTE  (OFF_U1 + 3*BH)

__device__ __forceinline__ float sigmoidf_(float x) { return 1.0f / (1.0f + expf(-x)); }

// ---------------------------------------------------------------------------
// Grid barrier: all-to-all flag protocol, device scope.
// Each WG release-publishes `epoch` to flags[wg]; first wave polls all 256.
// ---------------------------------------------------------------------------
__device__ __forceinline__ void grid_barrier(int* flags, int epoch) {
  __syncthreads();
  __threadfence();  // agent-scope release of this WG's phase writes
  if (threadIdx.x == 0)
    __hip_atomic_store(flags + blockIdx.x, epoch, __ATOMIC_RELAXED, __HIP_MEMORY_SCOPE_AGENT);
  if (threadIdx.x < 64) {
    const int base = (int)threadIdx.x * 4;
    for (;;) {
      int m0 = __hip_atomic_load(flags + base + 0, __ATOMIC_RELAXED, __HIP_MEMORY_SCOPE_AGENT);
      int m1 = __hip_atomic_load(flags + base + 1, __ATOMIC_RELAXED, __HIP_MEMORY_SCOPE_AGENT);
      int m2 = __hip_atomic_load(flags + base + 2, __ATOMIC_RELAXED, __HIP_MEMORY_SCOPE_AGENT);
      int m3 = __hip_atomic_load(flags + base + 3, __ATOMIC_RELAXED, __HIP_MEMORY_SCOPE_AGENT);
      bool ok = (m0 >= epoch) & (m1 >= epoch) & (m2 >= epoch) & (m3 >= epoch);
      if (__all(ok)) break;
      __builtin_amdgcn_s_sleep(2);
    }
  }
  __builtin_amdgcn_fence(__ATOMIC_ACQUIRE, "agent");  // invalidate stale cache lines
  __syncthreads();
}

// ---------------------------------------------------------------------------
// One GRU phase, computed by all 256 WGs.
// WG tile: 16 rows x 8 h-cols. Thread: kq=t&3 (K quarter), row=(t>>2)&15,
// col=(t>>6). Wave = 4 kq x 16 rows, col uniform -> weight loads are
// 4-distinct-address gathers (L1 broadcast over 16 row-lanes).
// NCHUNK input chunks of 256 each; last chunk is h_old (whh), rest wih.
// Gate partials reduced over the 4 kq lanes via shfl_xor; lane kq==0 does
// the gate math and writes h_new.
// ---------------------------------------------------------------------------
template <int NCHUNK>
__device__ void gru_phase(
    const float* __restrict__ xc0, const float* __restrict__ xc1,
    const float* __restrict__ xc2, const float* __restrict__ xc3,
    const float* __restrict__ wih, int wih_stride,
    const float* __restrict__ whh,
    const float* __restrict__ zadd,   // [B][768] precomputed z@W_z.T + bih, or null
    const float* __restrict__ bih,    // used when zadd == null
    const float* __restrict__ bhh,
    float* __restrict__ out0, float* __restrict__ out1,
    float* smem, int row0, int col0, int tid)
{
  __syncthreads();  // protect LDS reuse across phases
  // ---- stage chunks into LDS: [NCHUNK][16][260] (pad spreads b128 starts) ----
  const float* xc[4] = {xc0, xc1, xc2, xc3};
#pragma unroll
  for (int c = 0; c < NCHUNK; ++c) {
    const float* src = xc[c];
#pragma unroll
    for (int q = 0; q < 2; ++q) {
      int idx = q * NT + tid;           // 0..1023
      int rr = idx >> 6;
      int k4 = (idx & 63) << 2;
      float4 v = *reinterpret_cast<const float4*>(src + (size_t)(row0 + rr) * H + k4);
      *reinterpret_cast<float4*>(smem + c * 4160 + rr * 260 + k4) = v;
    }
  }
  __syncthreads();

  const int kq = tid & 3;
  const int row_l = (tid >> 2) & 15;
  const int col_l = tid >> 6;
  const int col = col0 + col_l;

  const int kstart = kq * (NCHUNK * 64);   // global k within [0, NCHUNK*256)
  const int c = kstart >> 8;               // chunk index
  const int koff = kstart & 255;           // offset within chunk
  const bool is_ih = (c < NCHUNK - 1);

  const float* wb;
  int wstr;
  if (is_ih) { wstr = wih_stride; wb = wih + (size_t)col * wstr + (c * 256 + koff); }
  else       { wstr = 256;        wb = whh + (size_t)col * 256 + koff; }
  const float* wR = wb;
  const float* wZ = wb + (size_t)256 * wstr;
  const float* wN = wb + (size_t)512 * wstr;
  const float* xr = smem + c * 4160 + row_l * 260 + koff;

  float aR = 0.f, aZ = 0.f, aN = 0.f;
  const int klen = NCHUNK * 64;
#pragma unroll 8
  for (int k = 0; k < klen; k += 4) {
    float4 xv = *reinterpret_cast<const float4*>(xr + k);
    float4 vR = *reinterpret_cast<const float4*>(wR + k);
    float4 vZ = *reinterpret_cast<const float4*>(wZ + k);
    float4 vN = *reinterpret_cast<const float4*>(wN + k);
    aR += xv.x * vR.x; aR += xv.y * vR.y; aR += xv.z * vR.z; aR += xv.w * vR.w;
    aZ += xv.x * vZ.x; aZ += xv.y * vZ.y; aZ += xv.z * vZ.z; aZ += xv.w * vZ.w;
    aN += xv.x * vN.x; aN += xv.y * vN.y; aN += xv.z * vN.z; aN += xv.w * vN.w;
  }
  float aNi = is_ih ? aN : 0.f;
  float aNh = is_ih ? 0.f : aN;
  // reduce over the 4 kq lanes (R/Z want the total; N needs ih and hh split)
#pragma unroll
  for (int m = 1; m <= 2; m <<= 1) {
    aR  += __shfl_xor(aR, m);
    aZ  += __shfl_xor(aZ, m);
    aNi += __shfl_xor(aNi, m);
    aNh += __shfl_xor(aNh, m);
  }
  if (kq == 0) {
    float bR, bZ, bN;
    if (zadd) {
      const float* zp = zadd + (size_t)(row0 + row_l) * G3;
      bR = zp[col]; bZ = zp[256 + col]; bN = zp[512 + col];
    } else {
      bR = bih[col]; bZ = bih[256 + col]; bN = bih[512 + col];
    }
    const float hR = bhh[col], hZ = bhh[256 + col], hN = bhh[512 + col];
    const float hold = smem[(NCHUNK - 1) * 4160 + row_l * 260 + col];
    const float rg = sigmoidf_(aR + bR + hR);
    const float ug = sigmoidf_(aZ + bZ + hZ);
    const float ng = tanhf(aNi + bN + rg * (aNh + hN));
    const float hnew = (1.f - ug) * ng + ug * hold;
    const size_t o = (size_t)(row0 + row_l) * H + col;
    out0[o] = hnew;
    if (out1) out1[o] = hnew;
  }
}

// ---------------------------------------------------------------------------
// Out phase: logits=(u+h2)@ow.T+ob, write d_out slice, argmax (first-index
// ties), note[row] = emb[argmax]. One WG per batch row (WGs >= B idle).
// ---------------------------------------------------------------------------
__device__ void out_phase(
    const float* __restrict__ u0i, const float* __restrict__ h2i,
    const float* __restrict__ ow, const float* __restrict__ ob,
    const float* __restrict__ embi,
    float* __restrict__ note_i, float* __restrict__ outp,
    float* smem, int* sidx, int w, int tid)
{
  if (w >= B) return;
  const int row = w;
  __syncthreads();
  if (tid < 64) {
    float4 a = *reinterpret_cast<const float4*>(u0i + (size_t)row * H + tid * 4);
    float4 b = *reinterpret_cast<const float4*>(h2i + (size_t)row * H + tid * 4);
    float4 s4; s4.x = a.x + b.x; s4.y = a.y + b.y; s4.z = a.z + b.z; s4.w = a.w + b.w;
    *reinterpret_cast<float4*>(smem + tid * 4) = s4;
  }
  __syncthreads();

  const int v = tid >> 2, kq = tid & 3;
#pragma unroll
  for (int p = 0; p < 2; ++p) {
    const int vv = v + p * 128;
    if (vv < V) {
      const float* wrow = ow + (size_t)vv * H + kq * 64;
      const float* xr = smem + kq * 64;
      float acc = 0.f;
#pragma unroll 4
      for (int k = 0; k < 64; k += 4) {
        float4 xv = *reinterpret_cast<const float4*>(xr + k);
        float4 wv = *reinterpret_cast<const float4*>(wrow + k);
        acc += xv.x * wv.x; acc += xv.y * wv.y; acc += xv.z * wv.z; acc += xv.w * wv.w;
      }
      acc += __shfl_xor(acc, 1);
      acc += __shfl_xor(acc, 2);
      if (kq == 0) {
        acc += ob[vv];
        outp[vv] = acc;
        smem[260 * 4 + vv] = acc;   // vals area (past xsum)
      }
    }
  }
  __syncthreads();
  if (tid < 64) {
    float* vals = smem + 260 * 4;
    float bv = vals[tid]; int bi = tid;
    float c1 = vals[64 + tid];
    if (c1 > bv) { bv = c1; bi = 64 + tid; }
    if (tid < 2) { float c2 = vals[128 + tid]; if (c2 > bv) { bv = c2; bi = 128 + tid; } }
#pragma unroll
    for (int off = 32; off; off >>= 1) {
      float ov = __shfl_down(bv, off);
      int oi = __shfl_down(bi, off);
      if (ov > bv || (ov == bv && oi < bi)) { bv = ov; bi = oi; }
    }
    if (tid == 0) *sidx = bi;
  }
  __syncthreads();
  const int idx = *sidx;
  if (tid < 64) {
    float4 e = *reinterpret_cast<const float4*>(embi + (size_t)idx * H + tid * 4);
    *reinterpret_cast<float4*>(note_i + (size_t)row * H + tid * 4) = e;
  }
}

// ---------------------------------------------------------------------------
// Persistent decode kernel: 256 WGs x 512 threads, whole 100-step loop.
// ---------------------------------------------------------------------------
__global__ __launch_bounds__(NT) void decoder_persistent(
    const float* __restrict__ g1wih, const float* __restrict__ g1whh,
    const float* __restrict__ g1bhh,
    const float* __restrict__ g2wih, const float* __restrict__ g2whh,
    const float* __restrict__ g2bhh,
    const float* __restrict__ cwih, const float* __restrict__ cwhh,
    const float* __restrict__ cbih, const float* __restrict__ cbhh,
    const float* __restrict__ outw, const float* __restrict__ outb,
    const float* __restrict__ emb,
    float* __restrict__ out, float* __restrict__ wsf)
{
  __shared__ float smem[4 * 4160];   // 66,560 B
  __shared__ int sidx;
  int* flags = reinterpret_cast<int*>(wsf) + OFF_FLAGS;
  float* Z1   = wsf + OFF_Z1;
  float* Z2   = wsf + OFF_Z2;
  float* g1h[2] = {wsf + OFF_G1HA, wsf + OFF_G1HB};
  float* h2b[2] = {wsf + OFF_H2A,  wsf + OFF_H2B};
  float* ctx[2] = {wsf + OFF_CTXA, wsf + OFF_CTXB};
  float* U0   = wsf + OFF_U0;
  float* U1   = wsf + OFF_U1;
  float* note = wsf + OFF_NOTE;

  const int w = blockIdx.x, tid = threadIdx.x;
  const int rb = w & 7, cb = w >> 3;
  const int row0 = rb * 16, col0 = cb * 8;
  int ep = 0;

  for (int t = 0; t < L; ++t) {
    const int rbk = t & 1, wbk = (t + 1) & 1;
    // ---- gru1, 3 independent streams (no grid barrier between) ----
    for (int s = 0; s < 3; ++s) {
      gru_phase<2>(note + (size_t)s * BH, g1h[rbk] + (size_t)s * BH, nullptr, nullptr,
                   g1wih + (size_t)s * G3 * 512, 512, g1whh + (size_t)s * G3 * H,
                   Z1 + (size_t)s * B * G3, nullptr, g1bhh + (size_t)s * G3,
                   g1h[wbk] + (size_t)s * BH, U0 + (size_t)s * BH,
                   smem, row0, col0, tid);
    }
    grid_barrier(flags, ++ep);
    for (int i = 0; i < 3; ++i) {
      const int j = 3 * t + i;
      const float* us0 = (0 < i ? U1 : U0) + 0 * BH;
      const float* us1 = (1 < i ? U1 : U0) + 1 * BH;
      const float* us2 = (2 < i ? U1 : U0) + 2 * BH;
      // ctx GRU (K = 768 ih + 256 hh)
      gru_phase<4>(us0, us1, us2, ctx[j & 1],
                   cwih, G3, cwhh,
                   nullptr, cbih, cbhh,
                   ctx[(j + 1) & 1], nullptr,
                   smem, row0, col0, tid);
      grid_barrier(flags, ++ep);
      // gru2[i]
      gru_phase<2>(ctx[(j + 1) & 1], h2b[rbk] + (size_t)i * BH, nullptr, nullptr,
                   g2wih + (size_t)i * G3 * 512, 512, g2whh + (size_t)i * G3 * H,
                   Z2 + (size_t)i * B * G3, nullptr, g2bhh + (size_t)i * G3,
                   h2b[wbk] + (size_t)i * BH, nullptr,
                   smem, row0, col0, tid);
      grid_barrier(flags, ++ep);
      // logits + argmax + note
      out_phase(U0 + (size_t)i * BH, h2b[wbk] + (size_t)i * BH,
                outw + (size_t)i * V * H, outb + (size_t)i * V, emb + (size_t)i * V * H,
                note + (size_t)i * BH,
                out + (size_t)i * B * L * V + (size_t)w * L * V + (size_t)t * V,
                smem, &sidx, w, tid);
      grid_barrier(flags, ++ep);
      // unroll-gru (fixed gru1[1] weights, faithful to reference)
      gru_phase<2>(note + (size_t)i * BH, U0 + (size_t)i * BH, nullptr, nullptr,
                   g1wih + (size_t)1 * G3 * 512, 512, g1whh + (size_t)1 * G3 * H,
                   Z1 + (size_t)1 * B * G3, nullptr, g1bhh + (size_t)1 * G3,
                   U1 + (size_t)i * BH, nullptr,
                   smem, row0, col0, tid);
      grid_barrier(flags, ++ep);
    }
  }
}

// ---------------------------------------------------------------------------
// Prologue kernels (outside the decode loop; cheap)
// ---------------------------------------------------------------------------
__global__ __launch_bounds__(256) void hid_kernel(
    const float* __restrict__ z, const float* __restrict__ hw,
    const float* __restrict__ hb, float* __restrict__ hidden)
{
  __shared__ float xs[32][260];
  const int tid = threadIdx.x;
  const int r = tid & 31, hc = tid >> 5;
  const int row0 = blockIdx.y * 32;
  const int col = blockIdx.x * 8 + hc;
  for (int jj = tid; jj < 32 * 64; jj += 256) {
    const int rr = jj >> 6, k4 = (jj & 63) << 2;
    *reinterpret_cast<float4*>(&xs[rr][k4]) =
        *reinterpret_cast<const float4*>(z + (size_t)(row0 + rr) * H + k4);
  }
  __syncthreads();
  float acc = 0.f;
  const float* wrow = hw + (size_t)col * H;
#pragma unroll 8
  for (int k = 0; k < 256; k += 4) {
    const float4 xv = *reinterpret_cast<const float4*>(&xs[r][k]);
    const float4 wv = *reinterpret_cast<const float4*>(wrow + k);
    acc += xv.x * wv.x; acc += xv.y * wv.y; acc += xv.z * wv.z; acc += xv.w * wv.w;
  }
  hidden[(size_t)(row0 + r) * H + col] = tanhf(acc + hb[col]);
}

__global__ __launch_bounds__(256) void zpre_kernel(
    const float* __restrict__ z, const float* __restrict__ wih,
    const float* __restrict__ bih, float* __restrict__ zout)
{
  __shared__ float xs[32][260];
  const int tid = threadIdx.x;
  const int r = tid & 31, hc = tid >> 5;
  const int row0 = blockIdx.y * 32;
  const int gr = blockIdx.x * 8 + hc;   // 0..2303
  const int s = gr / G3;
  const int g = gr - s * G3;
  for (int jj = tid; jj < 32 * 64; jj += 256) {
    const int rr = jj >> 6, k4 = (jj & 63) << 2;
    *reinterpret_cast<float4*>(&xs[rr][k4]) =
        *reinterpret_cast<const float4*>(z + (size_t)(row0 + rr) * H + k4);
  }
  __syncthreads();
  float acc = 0.f;
  const float* wrow = wih + (size_t)gr * 512 + 256;
#pragma unroll 8
  for (int k = 0; k < 256; k += 4) {
    const float4 xv = *reinterpret_cast<const float4*>(&xs[r][k]);
    const float4 wv = *reinterpret_cast<const float4*>(wrow + k);
    acc += xv.x * wv.x; acc += xv.y * wv.y; acc += xv.z * wv.z; acc += xv.w * wv.w;
  }
  zout[((size_t)(s * B + row0 + r)) * G3 + g] = acc + bih[gr];
}

__global__ __launch_bounds__(256) void init_copy(
    const float* __restrict__ hidden, float* __restrict__ g1h0,
    float* __restrict__ h20, float* __restrict__ ctx0)
{
  const int e = blockIdx.x * 256 + threadIdx.x;
  const float v = hidden[e];
  ctx0[e] = v;
  for (int s = 0; s < 3; ++s) {
    g1h0[(size_t)s * BH + e] = v;
    h20[(size_t)s * BH + e] = v;
  }
}

__global__ __launch_bounds__(256) void init_note(
    const float* __restrict__ emb, float* __restrict__ note)
{
  const int e = blockIdx.x * 256 + threadIdx.x;   // 0..3*B*H
  const int s = e / BH;
  const int c = e & (H - 1);
  note[e] = emb[(size_t)s * V * H + c];
}

__global__ void zero_flags(int* flags) { flags[threadIdx.x] = 0; }

extern "C" void kernel_launch(void* const* d_in, const int* in_sizes, int n_in,
                              void* d_out, int out_size, void* d_ws, size_t ws_size,
                              hipStream_t stream) {
  const float* z     = (const float*)d_in[0];
  const float* g1wih = (const float*)d_in[1];
  const float* g1whh = (const float*)d_in[2];
  const float* g1bih = (const float*)d_in[3];
  const float* g1bhh = (const float*)d_in[4];
  const float* g2wih = (const float*)d_in[5];
  const float* g2whh = (const float*)d_in[6];
  const float* g2bih = (const float*)d_in[7];
  const float* g2bhh = (const float*)d_in[8];
  const float* cwih  = (const float*)d_in[9];
  const float* cwhh  = (const float*)d_in[10];
  const float* cbih  = (const float*)d_in[11];
  const float* cbhh  = (const float*)d_in[12];
  const float* outw  = (const float*)d_in[13];
  const float* outb  = (const float*)d_in[14];
  const float* hidw  = (const float*)d_in[15];
  const float* hidb  = (const float*)d_in[16];
  const float* emb   = (const float*)d_in[17];
  float* out = (float*)d_out;
  float* wsf = (float*)d_ws;
  int* flags = (int*)d_ws;

  const dim3 blk(256);
  hid_kernel<<<dim3(32, 4), blk, 0, stream>>>(z, hidw, hidb, wsf + OFF_HID);
  zpre_kernel<<<dim3(288, 4), blk, 0, stream>>>(z, g1wih, g1bih, wsf + OFF_Z1);
  zpre_kernel<<<dim3(288, 4), blk, 0, stream>>>(z, g2wih, g2bih, wsf + OFF_Z2);
  init_copy<<<128, blk, 0, stream>>>(wsf + OFF_HID, wsf + OFF_G1HA,
                                     wsf + OFF_H2A, wsf + OFF_CTXA);
  init_note<<<384, blk, 0, stream>>>(emb, wsf + OFF_NOTE);
  zero_flags<<<1, 256, 0, stream>>>(flags);

  decoder_persistent<<<NWG, NT, 0, stream>>>(
      g1wih, g1whh, g1bhh, g2wih, g2whh, g2bhh,
      cwih, cwhh, cbih, cbhh, outw, outb, emb, out, wsf);
}

// Round 5
// 39678.192 us; speedup vs baseline: 2.5777x; 2.5777x over previous
//
#include <hip/hip_runtime.h>
#include <math.h>

#define B 128
#define H 256
#define V 130
#define L 100
#define G3 768
#define BH (B*H)
#define NWG 256
#define NT 512

// ---- workspace layout (4-byte words) ----
#define OFF_FLAGS 0               // 512 ints: 8 barrier counters, 64-int padded
#define OFF_HID   512
#define OFF_Z1    (OFF_HID + BH)
#define OFF_Z2    (OFF_Z1 + 3*B*G3)
#define OFF_G1HA  (OFF_Z2 + 3*B*G3)
#define OFF_G1HB  (OFF_G1HA + 3*BH)
#define OFF_H2A   (OFF_G1HB + 3*BH)
#define OFF_H2B   (OFF_H2A + 3*BH)
#define OFF_CTXA  (OFF_H2B + 3*BH)
#define OFF_CTXB  (OFF_CTXA + BH)
#define OFF_U0    (OFF_CTXB + BH)
#define OFF_U1    (OFF_U0 + 3*BH)
#define OFF_NOTE  (OFF_U1 + 3*BH)

typedef float v4f __attribute__((ext_vector_type(4)));

__device__ __forceinline__ float sigmoidf_(float x) { return 1.0f / (1.0f + expf(-x)); }

// ---- coherence-point (LLC) accessors: bypass L2 so no buffer_inv is needed;
// ---- weights keep normal cached loads and stay L2-warm across all steps.
__device__ __forceinline__ v4f load_coh4(const float* p) {
  v4f v;
  asm volatile("global_load_dwordx4 %0, %1, off sc0 sc1" : "=v"(v) : "v"(p) : "memory");
  return v;  // caller must s_waitcnt vmcnt before use
}
__device__ __forceinline__ void store_coh(float* p, float v) {
  asm volatile("global_store_dword %0, %1, off sc0 sc1" :: "v"(p), "v"(v) : "memory");
}
__device__ __forceinline__ void store_coh4(float* p, v4f v) {
  asm volatile("global_store_dwordx4 %0, %1, off sc0 sc1" :: "v"(p), "v"(v) : "memory");
}
__device__ __forceinline__ void waitvm0() {
  asm volatile("s_waitcnt vmcnt(0)" ::: "memory");
}

// ---------------------------------------------------------------------------
// Grid barrier: 8 padded arrival counters (atomicAdd), wave-0 polls 8 words.
// Data visibility comes from sc0/sc1 accesses + vmcnt(0) before arrival; the
// poll is relaxed (control dependency orders the subsequent coherent loads).
// ---------------------------------------------------------------------------
__device__ __forceinline__ void grid_barrier(int* cnt, int epoch) {
  waitvm0();                // all sc1 data stores of this wave are at LLC
  __syncthreads();          // every wave of this WG drained
  if (threadIdx.x == 0)
    __hip_atomic_fetch_add(cnt + (blockIdx.x & 7) * 64, 1,
                           __ATOMIC_RELAXED, __HIP_MEMORY_SCOPE_AGENT);
  if (threadIdx.x < 64) {
    const int lane = threadIdx.x;
    const int target = epoch * NWG;
    for (;;) {
      int c = 0;
      if (lane < 8)
        c = __hip_atomic_load(cnt + lane * 64, __ATOMIC_RELAXED, __HIP_MEMORY_SCOPE_AGENT);
      c += __shfl_xor(c, 1);
      c += __shfl_xor(c, 2);
      c += __shfl_xor(c, 4);
      if (__shfl(c, 0) >= target) break;
      __builtin_amdgcn_s_sleep(4);
    }
  }
  __syncthreads();
}

// ---------------------------------------------------------------------------
// One GRU phase. WG tile: 16 rows x 8 h-cols. Thread: kq=t&3, row=(t>>2)&15,
// col=t>>6. x chunks staged to LDS via coherent loads; weights via normal
// cached loads (L2-resident). Gate partials reduced over 4 kq lanes.
// ---------------------------------------------------------------------------
template <int NCHUNK>
__device__ void gru_phase(
    const float* __restrict__ xc0, const float* __restrict__ xc1,
    const float* __restrict__ xc2, const float* __restrict__ xc3,
    const float* __restrict__ wih, int wih_stride,
    const float* __restrict__ whh,
    const float* __restrict__ zadd,   // [B][768] precomputed z@W_z.T + bih, or null
    const float* __restrict__ bih,    // used when zadd == null
    const float* __restrict__ bhh,
    float* __restrict__ out0, float* __restrict__ out1,
    float* smem, int row0, int col0, int tid)
{
  const float* xc[4] = {xc0, xc1, xc2, xc3};
  // issue all staging loads (coherent, bypass L2) before the LDS sync
  v4f stg[2 * NCHUNK];
#pragma unroll
  for (int c = 0; c < NCHUNK; ++c) {
#pragma unroll
    for (int q = 0; q < 2; ++q) {
      const int idx = q * NT + tid;          // 0..1023
      const int rr = idx >> 6;
      const int k4 = (idx & 63) << 2;
      stg[c * 2 + q] = load_coh4(xc[c] + (size_t)(row0 + rr) * H + k4);
    }
  }
  __syncthreads();   // protect LDS reuse across phases (overlaps load latency)
  waitvm0();
#pragma unroll
  for (int c = 0; c < NCHUNK; ++c) {
#pragma unroll
    for (int q = 0; q < 2; ++q) {
      const int idx = q * NT + tid;
      const int rr = idx >> 6;
      const int k4 = (idx & 63) << 2;
      *reinterpret_cast<v4f*>(smem + c * 4160 + rr * 260 + k4) = stg[c * 2 + q];
    }
  }
  __syncthreads();

  const int kq = tid & 3;
  const int row_l = (tid >> 2) & 15;
  const int col_l = tid >> 6;
  const int col = col0 + col_l;

  const int kstart = kq * (NCHUNK * 64);
  const int c = kstart >> 8;
  const int koff = kstart & 255;
  const bool is_ih = (c < NCHUNK - 1);

  const float* wb;
  int wstr;
  if (is_ih) { wstr = wih_stride; wb = wih + (size_t)col * wstr + (c * 256 + koff); }
  else       { wstr = 256;        wb = whh + (size_t)col * 256 + koff; }
  const float* wR = wb;
  const float* wZ = wb + (size_t)256 * wstr;
  const float* wN = wb + (size_t)512 * wstr;
  const float* xr = smem + c * 4160 + row_l * 260 + koff;

  float aR = 0.f, aZ = 0.f, aN = 0.f;
  const int klen = NCHUNK * 64;
#pragma unroll 8
  for (int k = 0; k < klen; k += 4) {
    float4 xv = *reinterpret_cast<const float4*>(xr + k);
    float4 vR = *reinterpret_cast<const float4*>(wR + k);
    float4 vZ = *reinterpret_cast<const float4*>(wZ + k);
    float4 vN = *reinterpret_cast<const float4*>(wN + k);
    aR += xv.x * vR.x; aR += xv.y * vR.y; aR += xv.z * vR.z; aR += xv.w * vR.w;
    aZ += xv.x * vZ.x; aZ += xv.y * vZ.y; aZ += xv.z * vZ.z; aZ += xv.w * vZ.w;
    aN += xv.x * vN.x; aN += xv.y * vN.y; aN += xv.z * vN.z; aN += xv.w * vN.w;
  }
  float aNi = is_ih ? aN : 0.f;
  float aNh = is_ih ? 0.f : aN;
#pragma unroll
  for (int m = 1; m <= 2; m <<= 1) {
    aR  += __shfl_xor(aR, m);
    aZ  += __shfl_xor(aZ, m);
    aNi += __shfl_xor(aNi, m);
    aNh += __shfl_xor(aNh, m);
  }
  if (kq == 0) {
    float bR, bZ, bN;
    if (zadd) {
      const float* zp = zadd + (size_t)(row0 + row_l) * G3;
      bR = zp[col]; bZ = zp[256 + col]; bN = zp[512 + col];
    } else {
      bR = bih[col]; bZ = bih[256 + col]; bN = bih[512 + col];
    }
    const float hR = bhh[col], hZ = bhh[256 + col], hN = bhh[512 + col];
    const float hold = smem[(NCHUNK - 1) * 4160 + row_l * 260 + col];
    const float rg = sigmoidf_(aR + bR + hR);
    const float ug = sigmoidf_(aZ + bZ + hZ);
    const float ng = tanhf(aNi + bN + rg * (aNh + hN));
    const float hnew = (1.f - ug) * ng + ug * hold;
    const size_t o = (size_t)(row0 + row_l) * H + col;
    store_coh(out0 + o, hnew);
    if (out1) store_coh(out1 + o, hnew);
  }
}

// ---------------------------------------------------------------------------
// Out phase: logits=(u+h2)@ow.T+ob, write d_out slice, argmax (first-index
// ties), note[row] = emb[argmax]. One WG per batch row (WGs >= B idle).
// ---------------------------------------------------------------------------
__device__ void out_phase(
    const float* __restrict__ u0i, const float* __restrict__ h2i,
    const float* __restrict__ ow, const float* __restrict__ ob,
    const float* __restrict__ embi,
    float* __restrict__ note_i, float* __restrict__ outp,
    float* smem, int* sidx, int w, int tid)
{
  if (w >= B) return;
  const int row = w;
  v4f a4, b4;
  if (tid < 64) {
    a4 = load_coh4(u0i + (size_t)row * H + tid * 4);
    b4 = load_coh4(h2i + (size_t)row * H + tid * 4);
  }
  __syncthreads();
  if (tid < 64) {
    waitvm0();
    v4f s4 = a4 + b4;
    *reinterpret_cast<v4f*>(smem + tid * 4) = s4;
  }
  __syncthreads();

  const int v = tid >> 2, kq = tid & 3;
#pragma unroll
  for (int p = 0; p < 2; ++p) {
    const int vv = v + p * 128;
    if (vv < V) {
      const float* wrow = ow + (size_t)vv * H + kq * 64;
      const float* xr = smem + kq * 64;
      float acc = 0.f;
#pragma unroll 4
      for (int k = 0; k < 64; k += 4) {
        float4 xv = *reinterpret_cast<const float4*>(xr + k);
        float4 wv = *reinterpret_cast<const float4*>(wrow + k);
        acc += xv.x * wv.x; acc += xv.y * wv.y; acc += xv.z * wv.z; acc += xv.w * wv.w;
      }
      acc += __shfl_xor(acc, 1);
      acc += __shfl_xor(acc, 2);
      if (kq == 0) {
        acc += ob[vv];
        outp[vv] = acc;              // d_out: normal store, flushed at kernel end
        smem[260 * 4 + vv] = acc;    // vals area
      }
    }
  }
  __syncthreads();
  if (tid < 64) {
    float* vals = smem + 260 * 4;
    float bv = vals[tid]; int bi = tid;
    float c1 = vals[64 + tid];
    if (c1 > bv) { bv = c1; bi = 64 + tid; }
    if (tid < 2) { float c2 = vals[128 + tid]; if (c2 > bv) { bv = c2; bi = 128 + tid; } }
#pragma unroll
    for (int off = 32; off; off >>= 1) {
      float ov = __shfl_down(bv, off);
      int oi = __shfl_down(bi, off);
      if (ov > bv || (ov == bv && oi < bi)) { bv = ov; bi = oi; }
    }
    if (tid == 0) *sidx = bi;
  }
  __syncthreads();
  const int idx = *sidx;
  if (tid < 64) {
    const float* erow = embi + (size_t)idx * H + tid * 4;
    v4f e = *reinterpret_cast<const v4f*>(erow);   // emb read-only: cached
    store_coh4(note_i + (size_t)row * H + tid * 4, e);
  }
}

// ---------------------------------------------------------------------------
// Persistent decode kernel: 256 WGs x 512 threads, whole 100-step loop.
// ---------------------------------------------------------------------------
__global__ __launch_bounds__(NT) void decoder_persistent(
    const float* __restrict__ g1wih, const float* __restrict__ g1whh,
    const float* __restrict__ g1bhh,
    const float* __restrict__ g2wih, const float* __restrict__ g2whh,
    const float* __restrict__ g2bhh,
    const float* __restrict__ cwih, const float* __restrict__ cwhh,
    const float* __restrict__ cbih, const float* __restrict__ cbhh,
    const float* __restrict__ outw, const float* __restrict__ outb,
    const float* __restrict__ emb,
    float* __restrict__ out, float* __restrict__ wsf)
{
  __shared__ float smem[4 * 4160];   // 66,560 B
  __shared__ int sidx;
  int* cnt = reinterpret_cast<int*>(wsf) + OFF_FLAGS;
  float* Z1   = wsf + OFF_Z1;
  float* Z2   = wsf + OFF_Z2;
  float* g1h[2] = {wsf + OFF_G1HA, wsf + OFF_G1HB};
  float* h2b[2] = {wsf + OFF_H2A,  wsf + OFF_H2B};
  float* ctx[2] = {wsf + OFF_CTXA, wsf + OFF_CTXB};
  float* U0   = wsf + OFF_U0;
  float* U1   = wsf + OFF_U1;
  float* note = wsf + OFF_NOTE;

  const int w = blockIdx.x, tid = threadIdx.x;
  // cb = w&31: with round-robin XCD placement each XCD sees only 4 of 32
  // col-slices -> per-XCD weight footprint ~2.3MB, L2-resident.
  const int rb = w >> 5, cb = w & 31;
  const int row0 = rb * 16, col0 = cb * 8;
  int ep = 0;

  for (int t = 0; t < L; ++t) {
    const int rbk = t & 1, wbk = (t + 1) & 1;
    for (int s = 0; s < 3; ++s) {
      gru_phase<2>(note + (size_t)s * BH, g1h[rbk] + (size_t)s * BH, nullptr, nullptr,
                   g1wih + (size_t)s * G3 * 512, 512, g1whh + (size_t)s * G3 * H,
                   Z1 + (size_t)s * B * G3, nullptr, g1bhh + (size_t)s * G3,
                   g1h[wbk] + (size_t)s * BH, U0 + (size_t)s * BH,
                   smem, row0, col0, tid);
    }
    grid_barrier(cnt, ++ep);
    for (int i = 0; i < 3; ++i) {
      const int j = 3 * t + i;
      const float* us0 = (0 < i ? U1 : U0) + 0 * BH;
      const float* us1 = (1 < i ? U1 : U0) + 1 * BH;
      const float* us2 = (2 < i ? U1 : U0) + 2 * BH;
      gru_phase<4>(us0, us1, us2, ctx[j & 1],
                   cwih, G3, cwhh,
                   nullptr, cbih, cbhh,
                   ctx[(j + 1) & 1], nullptr,
                   smem, row0, col0, tid);
      grid_barrier(cnt, ++ep);
      gru_phase<2>(ctx[(j + 1) & 1], h2b[rbk] + (size_t)i * BH, nullptr, nullptr,
                   g2wih + (size_t)i * G3 * 512, 512, g2whh + (size_t)i * G3 * H,
                   Z2 + (size_t)i * B * G3, nullptr, g2bhh + (size_t)i * G3,
                   h2b[wbk] + (size_t)i * BH, nullptr,
                   smem, row0, col0, tid);
      grid_barrier(cnt, ++ep);
      out_phase(U0 + (size_t)i * BH, h2b[wbk] + (size_t)i * BH,
                outw + (size_t)i * V * H, outb + (size_t)i * V, emb + (size_t)i * V * H,
                note + (size_t)i * BH,
                out + (size_t)i * B * L * V + (size_t)w * L * V + (size_t)t * V,
                smem, &sidx, w, tid);
      grid_barrier(cnt, ++ep);
      gru_phase<2>(note + (size_t)i * BH, U0 + (size_t)i * BH, nullptr, nullptr,
                   g1wih + (size_t)1 * G3 * 512, 512, g1whh + (size_t)1 * G3 * H,
                   Z1 + (size_t)1 * B * G3, nullptr, g1bhh + (size_t)1 * G3,
                   U1 + (size_t)i * BH, nullptr,
                   smem, row0, col0, tid);
      grid_barrier(cnt, ++ep);
    }
  }
}

// ---------------------------------------------------------------------------
// Prologue kernels (outside the decode loop; cheap)
// ---------------------------------------------------------------------------
__global__ __launch_bounds__(256) void hid_kernel(
    const float* __restrict__ z, const float* __restrict__ hw,
    const float* __restrict__ hb, float* __restrict__ hidden)
{
  __shared__ float xs[32][260];
  const int tid = threadIdx.x;
  const int r = tid & 31, hc = tid >> 5;
  const int row0 = blockIdx.y * 32;
  const int col = blockIdx.x * 8 + hc;
  for (int jj = tid; jj < 32 * 64; jj += 256) {
    const int rr = jj >> 6, k4 = (jj & 63) << 2;
    *reinterpret_cast<float4*>(&xs[rr][k4]) =
        *reinterpret_cast<const float4*>(z + (size_t)(row0 + rr) * H + k4);
  }
  __syncthreads();
  float acc = 0.f;
  const float* wrow = hw + (size_t)col * H;
#pragma unroll 8
  for (int k = 0; k < 256; k += 4) {
    const float4 xv = *reinterpret_cast<const float4*>(&xs[r][k]);
    const float4 wv = *reinterpret_cast<const float4*>(wrow + k);
    acc += xv.x * wv.x; acc += xv.y * wv.y; acc += xv.z * wv.z; acc += xv.w * wv.w;
  }
  hidden[(size_t)(row0 + r) * H + col] = tanhf(acc + hb[col]);
}

__global__ __launch_bounds__(256) void zpre_kernel(
    const float* __restrict__ z, const float* __restrict__ wih,
    const float* __restrict__ bih, float* __restrict__ zout)
{
  __shared__ float xs[32][260];
  const int tid = threadIdx.x;
  const int r = tid & 31, hc = tid >> 5;
  const int row0 = blockIdx.y * 32;
  const int gr = blockIdx.x * 8 + hc;   // 0..2303
  const int s = gr / G3;
  const int g = gr - s * G3;
  for (int jj = tid; jj < 32 * 64; jj += 256) {
    const int rr = jj >> 6, k4 = (jj & 63) << 2;
    *reinterpret_cast<float4*>(&xs[rr][k4]) =
        *reinterpret_cast<const float4*>(z + (size_t)(row0 + rr) * H + k4);
  }
  __syncthreads();
  float acc = 0.f;
  const float* wrow = wih + (size_t)gr * 512 + 256;
#pragma unroll 8
  for (int k = 0; k < 256; k += 4) {
    const float4 xv = *reinterpret_cast<const float4*>(&xs[r][k]);
    const float4 wv = *reinterpret_cast<const float4*>(wrow + k);
    acc += xv.x * wv.x; acc += xv.y * wv.y; acc += xv.z * wv.z; acc += xv.w * wv.w;
  }
  zout[((size_t)(s * B + row0 + r)) * G3 + g] = acc + bih[gr];
}

__global__ __launch_bounds__(256) void init_copy(
    const float* __restrict__ hidden, float* __restrict__ g1h0,
    float* __restrict__ h20, float* __restrict__ ctx0)
{
  const int e = blockIdx.x * 256 + threadIdx.x;
  const float v = hidden[e];
  ctx0[e] = v;
  for (int s = 0; s < 3; ++s) {
    g1h0[(size_t)s * BH + e] = v;
    h20[(size_t)s * BH + e] = v;
  }
}

__global__ __launch_bounds__(256) void init_note(
    const float* __restrict__ emb, float* __restrict__ note)
{
  const int e = blockIdx.x * 256 + threadIdx.x;   // 0..3*B*H
  const int s = e / BH;
  const int c = e & (H - 1);
  note[e] = emb[(size_t)s * V * H + c];
}

__global__ void zero_flags(int* flags) { flags[threadIdx.x] = 0; }

extern "C" void kernel_launch(void* const* d_in, const int* in_sizes, int n_in,
                              void* d_out, int out_size, void* d_ws, size_t ws_size,
                              hipStream_t stream) {
  const float* z     = (const float*)d_in[0];
  const float* g1wih = (const float*)d_in[1];
  const float* g1whh = (const float*)d_in[2];
  const float* g1bih = (const float*)d_in[3];
  const float* g1bhh = (const float*)d_in[4];
  const float* g2wih = (const float*)d_in[5];
  const float* g2whh = (const float*)d_in[6];
  const float* g2bih = (const float*)d_in[7];
  const float* g2bhh = (const float*)d_in[8];
  const float* cwih  = (const float*)d_in[9];
  const float* cwhh  = (const float*)d_in[10];
  const float* cbih  = (const float*)d_in[11];
  const float* cbhh  = (const float*)d_in[12];
  const float* outw  = (const float*)d_in[13];
  const float* outb  = (const float*)d_in[14];
  const float* hidw  = (const float*)d_in[15];
  const float* hidb  = (const float*)d_in[16];
  const float* emb   = (const float*)d_in[17];
  float* out = (float*)d_out;
  float* wsf = (float*)d_ws;
  int* flags = (int*)d_ws;

  const dim3 blk(256);
  hid_kernel<<<dim3(32, 4), blk, 0, stream>>>(z, hidw, hidb, wsf + OFF_HID);
  zpre_kernel<<<dim3(288, 4), blk, 0, stream>>>(z, g1wih, g1bih, wsf + OFF_Z1);
  zpre_kernel<<<dim3(288, 4), blk, 0, stream>>>(z, g2wih, g2bih, wsf + OFF_Z2);
  init_copy<<<128, blk, 0, stream>>>(wsf + OFF_HID, wsf + OFF_G1HA,
                                     wsf + OFF_H2A, wsf + OFF_CTXA);
  init_note<<<384, blk, 0, stream>>>(emb, wsf + OFF_NOTE);
  zero_flags<<<1, 512, 0, stream>>>(flags);

  decoder_persistent<<<NWG, NT, 0, stream>>>(
      g1wih, g1whh, g1bhh, g2wih, g2whh, g2bhh,
      cwih, cwhh, cbih, cbhh, outw, outb, emb, out, wsf);
}

// Round 6
// 39428.970 us; speedup vs baseline: 2.5939x; 1.0063x over previous
//
#include <hip/hip_runtime.h>
#include <math.h>

#define B 128
#define H 256
#define V 130
#define L 100
#define G3 768
#define BH (B*H)
#define NWG 256
#define NT 512

// ---- workspace layout (4-byte words) ----
// flags: 32 barrier counters x 16-int pad = 512
// xrank: 8 per-XCD rank counters x 16-int pad = 128 (at +512)
// claim: 256 tile-claim words (at +640)
#define OFF_FLAGS 0
#define OFF_XRANK 512
#define OFF_CLAIM 640
#define OFF_HID   1024
#define OFF_Z1    (OFF_HID + BH)
#define OFF_Z2    (OFF_Z1 + 3*B*G3)
#define OFF_G1HA  (OFF_Z2 + 3*B*G3)
#define OFF_G1HB  (OFF_G1HA + 3*BH)
#define OFF_H2A   (OFF_G1HB + 3*BH)
#define OFF_H2B   (OFF_H2A + 3*BH)
#define OFF_CTXA  (OFF_H2B + 3*BH)
#define OFF_CTXB  (OFF_CTXA + BH)
#define OFF_U0    (OFF_CTXB + BH)
#define OFF_U1    (OFF_U0 + 3*BH)
#define OFF_NOTE  (OFF_U1 + 3*BH)

typedef float v4f __attribute__((ext_vector_type(4)));

__device__ __forceinline__ float sigmoidf_(float x) { return 1.0f / (1.0f + expf(-x)); }

// ---- coherence-point (LLC) accessors: bypass L2 so no buffer_inv is needed;
// ---- weights keep normal cached loads and stay L2-warm across all steps.
__device__ __forceinline__ v4f load_coh4(const float* p) {
  v4f v;
  asm volatile("global_load_dwordx4 %0, %1, off sc0 sc1" : "=v"(v) : "v"(p) : "memory");
  return v;  // caller must s_waitcnt vmcnt before use
}
__device__ __forceinline__ void store_coh(float* p, float v) {
  asm volatile("global_store_dword %0, %1, off sc0 sc1" :: "v"(p), "v"(v) : "memory");
}
__device__ __forceinline__ void store_coh4(float* p, v4f v) {
  asm volatile("global_store_dwordx4 %0, %1, off sc0 sc1" :: "v"(p), "v"(v) : "memory");
}
__device__ __forceinline__ void waitvm0() {
  asm volatile("s_waitcnt vmcnt(0)" ::: "memory");
}

// ---------------------------------------------------------------------------
// Grid barrier: 32 padded arrival counters (8 serialized RMWs each), wave-0
// polls all 32 with a butterfly sum. Data visibility: sc0/sc1 accesses +
// vmcnt(0) before arrival; poll is relaxed (control dep orders later loads).
// ---------------------------------------------------------------------------
__device__ __forceinline__ void grid_barrier(int* cnt, int epoch) {
  waitvm0();                // all sc1 data stores of this wave are at LLC
  __syncthreads();          // every wave of this WG drained
  if (threadIdx.x == 0)
    __hip_atomic_fetch_add(cnt + (blockIdx.x & 31) * 16, 1,
                           __ATOMIC_RELAXED, __HIP_MEMORY_SCOPE_AGENT);
  if (threadIdx.x < 64) {
    const int lane = threadIdx.x;
    const int target = epoch * NWG;
    for (;;) {
      int c = 0;
      if (lane < 32)
        c = __hip_atomic_load(cnt + lane * 16, __ATOMIC_RELAXED, __HIP_MEMORY_SCOPE_AGENT);
      c += __shfl_xor(c, 1);
      c += __shfl_xor(c, 2);
      c += __shfl_xor(c, 4);
      c += __shfl_xor(c, 8);
      c += __shfl_xor(c, 16);
      if (__shfl(c, 0) >= target) break;
      __builtin_amdgcn_s_sleep(2);
    }
  }
  __syncthreads();
}

// ---------------------------------------------------------------------------
// One GRU phase. WG tile: 16 rows x 8 h-cols. Thread: kq=t&3, row=(t>>2)&15,
// col=t>>6. x chunks staged to LDS via coherent loads; weights via normal
// cached loads (L2-resident per-XCD thanks to the XCC-aware tile claim).
// ---------------------------------------------------------------------------
template <int NCHUNK>
__device__ void gru_phase(
    const float* __restrict__ xc0, const float* __restrict__ xc1,
    const float* __restrict__ xc2, const float* __restrict__ xc3,
    const float* __restrict__ wih, int wih_stride,
    const float* __restrict__ whh,
    const float* __restrict__ zadd,   // [B][768] precomputed z@W_z.T + bih, or null
    const float* __restrict__ bih,    // used when zadd == null
    const float* __restrict__ bhh,
    float* __restrict__ out0, float* __restrict__ out1,
    float* smem, int row0, int col0, int tid)
{
  const float* xc[4] = {xc0, xc1, xc2, xc3};
  // issue all staging loads (coherent, bypass L2) before the LDS sync
  v4f stg[2 * NCHUNK];
#pragma unroll
  for (int c = 0; c < NCHUNK; ++c) {
#pragma unroll
    for (int q = 0; q < 2; ++q) {
      const int idx = q * NT + tid;          // 0..1023
      const int rr = idx >> 6;
      const int k4 = (idx & 63) << 2;
      stg[c * 2 + q] = load_coh4(xc[c] + (size_t)(row0 + rr) * H + k4);
    }
  }
  __syncthreads();   // protect LDS reuse across phases (overlaps load latency)
  waitvm0();
#pragma unroll
  for (int c = 0; c < NCHUNK; ++c) {
#pragma unroll
    for (int q = 0; q < 2; ++q) {
      const int idx = q * NT + tid;
      const int rr = idx >> 6;
      const int k4 = (idx & 63) << 2;
      *reinterpret_cast<v4f*>(smem + c * 4160 + rr * 260 + k4) = stg[c * 2 + q];
    }
  }
  __syncthreads();

  const int kq = tid & 3;
  const int row_l = (tid >> 2) & 15;
  const int col_l = tid >> 6;
  const int col = col0 + col_l;

  const int kstart = kq * (NCHUNK * 64);
  const int c = kstart >> 8;
  const int koff = kstart & 255;
  const bool is_ih = (c < NCHUNK - 1);

  const float* wb;
  int wstr;
  if (is_ih) { wstr = wih_stride; wb = wih + (size_t)col * wstr + (c * 256 + koff); }
  else       { wstr = 256;        wb = whh + (size_t)col * 256 + koff; }
  const float* wR = wb;
  const float* wZ = wb + (size_t)256 * wstr;
  const float* wN = wb + (size_t)512 * wstr;
  const float* xr = smem + c * 4160 + row_l * 260 + koff;

  float aR = 0.f, aZ = 0.f, aN = 0.f;
  const int klen = NCHUNK * 64;
#pragma unroll 8
  for (int k = 0; k < klen; k += 4) {
    float4 xv = *reinterpret_cast<const float4*>(xr + k);
    float4 vR = *reinterpret_cast<const float4*>(wR + k);
    float4 vZ = *reinterpret_cast<const float4*>(wZ + k);
    float4 vN = *reinterpret_cast<const float4*>(wN + k);
    aR += xv.x * vR.x; aR += xv.y * vR.y; aR += xv.z * vR.z; aR += xv.w * vR.w;
    aZ += xv.x * vZ.x; aZ += xv.y * vZ.y; aZ += xv.z * vZ.z; aZ += xv.w * vZ.w;
    aN += xv.x * vN.x; aN += xv.y * vN.y; aN += xv.z * vN.z; aN += xv.w * vN.w;
  }
  float aNi = is_ih ? aN : 0.f;
  float aNh = is_ih ? 0.f : aN;
#pragma unroll
  for (int m = 1; m <= 2; m <<= 1) {
    aR  += __shfl_xor(aR, m);
    aZ  += __shfl_xor(aZ, m);
    aNi += __shfl_xor(aNi, m);
    aNh += __shfl_xor(aNh, m);
  }
  if (kq == 0) {
    float bR, bZ, bN;
    if (zadd) {
      const float* zp = zadd + (size_t)(row0 + row_l) * G3;
      bR = zp[col]; bZ = zp[256 + col]; bN = zp[512 + col];
    } else {
      bR = bih[col]; bZ = bih[256 + col]; bN = bih[512 + col];
    }
    const float hR = bhh[col], hZ = bhh[256 + col], hN = bhh[512 + col];
    const float hold = smem[(NCHUNK - 1) * 4160 + row_l * 260 + col];
    const float rg = sigmoidf_(aR + bR + hR);
    const float ug = sigmoidf_(aZ + bZ + hZ);
    const float ng = tanhf(aNi + bN + rg * (aNh + hN));
    const float hnew = (1.f - ug) * ng + ug * hold;
    const size_t o = (size_t)(row0 + row_l) * H + col;
    store_coh(out0 + o, hnew);
    if (out1) store_coh(out1 + o, hnew);
  }
}

// ---------------------------------------------------------------------------
// Out phase: logits=(u+h2)@ow.T+ob, write d_out slice, argmax (first-index
// ties), note[row] = emb[argmax]. One WG per batch row (WGs >= B idle).
// ---------------------------------------------------------------------------
__device__ void out_phase(
    const float* __restrict__ u0i, const float* __restrict__ h2i,
    const float* __restrict__ ow, const float* __restrict__ ob,
    const float* __restrict__ embi,
    float* __restrict__ note_i, float* __restrict__ outp,
    float* smem, int* sidx, int w, int tid)
{
  if (w >= B) return;
  const int row = w;
  v4f a4, b4;
  if (tid < 64) {
    a4 = load_coh4(u0i + (size_t)row * H + tid * 4);
    b4 = load_coh4(h2i + (size_t)row * H + tid * 4);
  }
  __syncthreads();
  if (tid < 64) {
    waitvm0();
    v4f s4 = a4 + b4;
    *reinterpret_cast<v4f*>(smem + tid * 4) = s4;
  }
  __syncthreads();

  const int v = tid >> 2, kq = tid & 3;
#pragma unroll
  for (int p = 0; p < 2; ++p) {
    const int vv = v + p * 128;
    if (vv < V) {
      const float* wrow = ow + (size_t)vv * H + kq * 64;
      const float* xr = smem + kq * 64;
      float acc = 0.f;
#pragma unroll 4
      for (int k = 0; k < 64; k += 4) {
        float4 xv = *reinterpret_cast<const float4*>(xr + k);
        float4 wv = *reinterpret_cast<const float4*>(wrow + k);
        acc += xv.x * wv.x; acc += xv.y * wv.y; acc += xv.z * wv.z; acc += xv.w * wv.w;
      }
      acc += __shfl_xor(acc, 1);
      acc += __shfl_xor(acc, 2);
      if (kq == 0) {
        acc += ob[vv];
        outp[vv] = acc;              // d_out: normal store, flushed at kernel end
        smem[260 * 4 + vv] = acc;    // vals area
      }
    }
  }
  __syncthreads();
  if (tid < 64) {
    float* vals = smem + 260 * 4;
    float bv = vals[tid]; int bi = tid;
    float c1 = vals[64 + tid];
    if (c1 > bv) { bv = c1; bi = 64 + tid; }
    if (tid < 2) { float c2 = vals[128 + tid]; if (c2 > bv) { bv = c2; bi = 128 + tid; } }
#pragma unroll
    for (int off = 32; off; off >>= 1) {
      float ov = __shfl_down(bv, off);
      int oi = __shfl_down(bi, off);
      if (ov > bv || (ov == bv && oi < bi)) { bv = ov; bi = oi; }
    }
    if (tid == 0) *sidx = bi;
  }
  __syncthreads();
  const int idx = *sidx;
  if (tid < 64) {
    const float* erow = embi + (size_t)idx * H + tid * 4;
    v4f e = *reinterpret_cast<const v4f*>(erow);   // emb read-only: cached
    store_coh4(note_i + (size_t)row * H + tid * 4, e);
  }
}

// ---------------------------------------------------------------------------
// Persistent decode kernel: 256 WGs x 512 threads, whole 100-step loop.
// LDS oversized past 80KB -> exactly 1 WG/CU -> exactly 32 WGs per XCD.
// Tile claim: col-slice by physical XCD (weights L2-resident per XCD),
// CAS claim table keeps it correct under any placement.
// ---------------------------------------------------------------------------
__global__ __launch_bounds__(NT) void decoder_persistent(
    const float* __restrict__ g1wih, const float* __restrict__ g1whh,
    const float* __restrict__ g1bhh,
    const float* __restrict__ g2wih, const float* __restrict__ g2whh,
    const float* __restrict__ g2bhh,
    const float* __restrict__ cwih, const float* __restrict__ cwhh,
    const float* __restrict__ cbih, const float* __restrict__ cbhh,
    const float* __restrict__ outw, const float* __restrict__ outb,
    const float* __restrict__ emb,
    float* __restrict__ out, float* __restrict__ wsf)
{
  __shared__ float smem[20608];   // 82,432 B > 80 KiB -> 1 WG/CU
  __shared__ int sidx;
  __shared__ int s_tile;
  int* cnt   = reinterpret_cast<int*>(wsf) + OFF_FLAGS;
  int* xrank = reinterpret_cast<int*>(wsf) + OFF_XRANK;
  int* claim = reinterpret_cast<int*>(wsf) + OFF_CLAIM;
  float* Z1   = wsf + OFF_Z1;
  float* Z2   = wsf + OFF_Z2;
  float* g1h[2] = {wsf + OFF_G1HA, wsf + OFF_G1HB};
  float* h2b[2] = {wsf + OFF_H2A,  wsf + OFF_H2B};
  float* ctx[2] = {wsf + OFF_CTXA, wsf + OFF_CTXB};
  float* U0   = wsf + OFF_U0;
  float* U1   = wsf + OFF_U1;
  float* note = wsf + OFF_NOTE;

  const int w = blockIdx.x, tid = threadIdx.x;

  // ---- XCC-aware tile claim (thread 0) ----
  if (tid == 0) {
    int xcc;
    asm("s_getreg_b32 %0, hwreg(20, 0, 32)" : "=s"(xcc));  // 20 = HW_REG_XCC_ID
    xcc &= 7;
    int rk = __hip_atomic_fetch_add(xrank + xcc * 16, 1,
                                    __ATOMIC_RELAXED, __HIP_MEMORY_SCOPE_AGENT);
    int tile = (rk < 32) ? (xcc * 32 + rk) : (w & 255);
    for (;;) {
      if (atomicCAS(claim + tile, 0, 1) == 0) break;   // unique claim
      tile = (tile + 1) & 255;
    }
    s_tile = tile;
  }
  __syncthreads();
  const int tile = s_tile;
  // tile = xcc*32 + rank ; rank = subcb(2b) | rb(3b)<<2
  const int col0 = (tile >> 5) * 32 + (tile & 3) * 8;
  const int row0 = ((tile >> 2) & 7) * 16;
  int ep = 0;

  for (int t = 0; t < L; ++t) {
    const int rbk = t & 1, wbk = (t + 1) & 1;
    for (int s = 0; s < 3; ++s) {
      gru_phase<2>(note + (size_t)s * BH, g1h[rbk] + (size_t)s * BH, nullptr, nullptr,
                   g1wih + (size_t)s * G3 * 512, 512, g1whh + (size_t)s * G3 * H,
                   Z1 + (size_t)s * B * G3, nullptr, g1bhh + (size_t)s * G3,
                   g1h[wbk] + (size_t)s * BH, U0 + (size_t)s * BH,
                   smem, row0, col0, tid);
    }
    grid_barrier(cnt, ++ep);
    for (int i = 0; i < 3; ++i) {
      const int j = 3 * t + i;
      const float* us0 = (0 < i ? U1 : U0) + 0 * BH;
      const float* us1 = (1 < i ? U1 : U0) + 1 * BH;
      const float* us2 = (2 < i ? U1 : U0) + 2 * BH;
      gru_phase<4>(us0, us1, us2, ctx[j & 1],
                   cwih, G3, cwhh,
                   nullptr, cbih, cbhh,
                   ctx[(j + 1) & 1], nullptr,
                   smem, row0, col0, tid);
      grid_barrier(cnt, ++ep);
      gru_phase<2>(ctx[(j + 1) & 1], h2b[rbk] + (size_t)i * BH, nullptr, nullptr,
                   g2wih + (size_t)i * G3 * 512, 512, g2whh + (size_t)i * G3 * H,
                   Z2 + (size_t)i * B * G3, nullptr, g2bhh + (size_t)i * G3,
                   h2b[wbk] + (size_t)i * BH, nullptr,
                   smem, row0, col0, tid);
      grid_barrier(cnt, ++ep);
      out_phase(U0 + (size_t)i * BH, h2b[wbk] + (size_t)i * BH,
                outw + (size_t)i * V * H, outb + (size_t)i * V, emb + (size_t)i * V * H,
                note + (size_t)i * BH,
                out + (size_t)i * B * L * V + (size_t)w * L * V + (size_t)t * V,
                smem, &sidx, w, tid);
      grid_barrier(cnt, ++ep);
      gru_phase<2>(note + (size_t)i * BH, U0 + (size_t)i * BH, nullptr, nullptr,
                   g1wih + (size_t)1 * G3 * 512, 512, g1whh + (size_t)1 * G3 * H,
                   Z1 + (size_t)1 * B * G3, nullptr, g1bhh + (size_t)1 * G3,
                   U1 + (size_t)i * BH, nullptr,
                   smem, row0, col0, tid);
      grid_barrier(cnt, ++ep);
    }
  }
}

// ---------------------------------------------------------------------------
// Prologue kernels (outside the decode loop; cheap)
// ---------------------------------------------------------------------------
__global__ __launch_bounds__(256) void hid_kernel(
    const float* __restrict__ z, const float* __restrict__ hw,
    const float* __restrict__ hb, float* __restrict__ hidden)
{
  __shared__ float xs[32][260];
  const int tid = threadIdx.x;
  const int r = tid & 31, hc = tid >> 5;
  const int row0 = blockIdx.y * 32;
  const int col = blockIdx.x * 8 + hc;
  for (int jj = tid; jj < 32 * 64; jj += 256) {
    const int rr = jj >> 6, k4 = (jj & 63) << 2;
    *reinterpret_cast<float4*>(&xs[rr][k4]) =
        *reinterpret_cast<const float4*>(z + (size_t)(row0 + rr) * H + k4);
  }
  __syncthreads();
  float acc = 0.f;
  const float* wrow = hw + (size_t)col * H;
#pragma unroll 8
  for (int k = 0; k < 256; k += 4) {
    const float4 xv = *reinterpret_cast<const float4*>(&xs[r][k]);
    const float4 wv = *reinterpret_cast<const float4*>(wrow + k);
    acc += xv.x * wv.x; acc += xv.y * wv.y; acc += xv.z * wv.z; acc += xv.w * wv.w;
  }
  hidden[(size_t)(row0 + r) * H + col] = tanhf(acc + hb[col]);
}

__global__ __launch_bounds__(256) void zpre_kernel(
    const float* __restrict__ z, const float* __restrict__ wih,
    const float* __restrict__ bih, float* __restrict__ zout)
{
  __shared__ float xs[32][260];
  const int tid = threadIdx.x;
  const int r = tid & 31, hc = tid >> 5;
  const int row0 = blockIdx.y * 32;
  const int gr = blockIdx.x * 8 + hc;   // 0..2303
  const int s = gr / G3;
  const int g = gr - s * G3;
  for (int jj = tid; jj < 32 * 64; jj += 256) {
    const int rr = jj >> 6, k4 = (jj & 63) << 2;
    *reinterpret_cast<float4*>(&xs[rr][k4]) =
        *reinterpret_cast<const float4*>(z + (size_t)(row0 + rr) * H + k4);
  }
  __syncthreads();
  float acc = 0.f;
  const float* wrow = wih + (size_t)gr * 512 + 256;
#pragma unroll 8
  for (int k = 0; k < 256; k += 4) {
    const float4 xv = *reinterpret_cast<const float4*>(&xs[r][k]);
    const float4 wv = *reinterpret_cast<const float4*>(wrow + k);
    acc += xv.x * wv.x; acc += xv.y * wv.y; acc += xv.z * wv.z; acc += xv.w * wv.w;
  }
  zout[((size_t)(s * B + row0 + r)) * G3 + g] = acc + bih[gr];
}

__global__ __launch_bounds__(256) void init_copy(
    const float* __restrict__ hidden, float* __restrict__ g1h0,
    float* __restrict__ h20, float* __restrict__ ctx0)
{
  const int e = blockIdx.x * 256 + threadIdx.x;
  const float v = hidden[e];
  ctx0[e] = v;
  for (int s = 0; s < 3; ++s) {
    g1h0[(size_t)s * BH + e] = v;
    h20[(size_t)s * BH + e] = v;
  }
}

__global__ __launch_bounds__(256) void init_note(
    const float* __restrict__ emb, float* __restrict__ note)
{
  const int e = blockIdx.x * 256 + threadIdx.x;   // 0..3*B*H
  const int s = e / BH;
  const int c = e & (H - 1);
  note[e] = emb[(size_t)s * V * H + c];
}

__global__ void zero_flags(int* flags) { flags[threadIdx.x] = 0; }

extern "C" void kernel_launch(void* const* d_in, const int* in_sizes, int n_in,
                              void* d_out, int out_size, void* d_ws, size_t ws_size,
                              hipStream_t stream) {
  const float* z     = (const float*)d_in[0];
  const float* g1wih = (const float*)d_in[1];
  const float* g1whh = (const float*)d_in[2];
  const float* g1bih = (const float*)d_in[3];
  const float* g1bhh = (const float*)d_in[4];
  const float* g2wih = (const float*)d_in[5];
  const float* g2whh = (const float*)d_in[6];
  const float* g2bih = (const float*)d_in[7];
  const float* g2bhh = (const float*)d_in[8];
  const float* cwih  = (const float*)d_in[9];
  const float* cwhh  = (const float*)d_in[10];
  const float* cbih  = (const float*)d_in[11];
  const float* cbhh  = (const float*)d_in[12];
  const float* outw  = (const float*)d_in[13];
  const float* outb  = (const float*)d_in[14];
  const float* hidw  = (const float*)d_in[15];
  const float* hidb  = (const float*)d_in[16];
  const float* emb   = (const float*)d_in[17];
  float* out = (float*)d_out;
  float* wsf = (float*)d_ws;
  int* flags = (int*)d_ws;

  const dim3 blk(256);
  hid_kernel<<<dim3(32, 4), blk, 0, stream>>>(z, hidw, hidb, wsf + OFF_HID);
  zpre_kernel<<<dim3(288, 4), blk, 0, stream>>>(z, g1wih, g1bih, wsf + OFF_Z1);
  zpre_kernel<<<dim3(288, 4), blk, 0, stream>>>(z, g2wih, g2bih, wsf + OFF_Z2);
  init_copy<<<128, blk, 0, stream>>>(wsf + OFF_HID, wsf + OFF_G1HA,
                                     wsf + OFF_H2A, wsf + OFF_CTXA);
  init_note<<<384, blk, 0, stream>>>(emb, wsf + OFF_NOTE);
  zero_flags<<<1, 1024, 0, stream>>>(flags);

  decoder_persistent<<<NWG, NT, 0, stream>>>(
      g1wih, g1whh, g1bhh, g2wih, g2whh, g2bhh,
      cwih, cwhh, cbih, cbhh, outw, outb, emb, out, wsf);
}

// Round 7
// 37775.705 us; speedup vs baseline: 2.7075x; 1.0438x over previous
//
#include <hip/hip_runtime.h>
#include <math.h>

#define B 128
#define H 256
#define V 130
#define L 100
#define G3 768
#define BH (B*H)
#define NWG 256
#define NT 1024

// ---- workspace layout (4-byte words) ----
// flags: 32 group counters x 16-int pad = 512
// xrank: 8 per-XCD rank counters x 16-int pad = 128 (at +512)
// claim: 256 tile-claim words (at +640)
#define OFF_FLAGS 0
#define OFF_XRANK 512
#define OFF_CLAIM 640
#define OFF_HID   1024
#define OFF_Z1    (OFF_HID + BH)
#define OFF_Z2    (OFF_Z1 + 3*B*G3)
#define OFF_G1HA  (OFF_Z2 + 3*B*G3)
#define OFF_G1HB  (OFF_G1HA + 3*BH)
#define OFF_H2A   (OFF_G1HB + 3*BH)
#define OFF_H2B   (OFF_H2A + 3*BH)
#define OFF_CTXA  (OFF_H2B + 3*BH)
#define OFF_CTXB  (OFF_CTXA + BH)
#define OFF_U0    (OFF_CTXB + BH)
#define OFF_U1    (OFF_U0 + 3*BH)
#define OFF_NOTE  (OFF_U1 + 3*BH)

typedef float v4f __attribute__((ext_vector_type(4)));

__device__ __forceinline__ float sigmoidf_(float x) { return 1.0f / (1.0f + expf(-x)); }

// ---- coherence-point (LLC) accessors for cross-WG activations; weights and
// ---- biases use normal cached loads (L2-resident per XCD).
__device__ __forceinline__ v4f load_coh4(const float* p) {
  v4f v;
  asm volatile("global_load_dwordx4 %0, %1, off sc0 sc1" : "=v"(v) : "v"(p) : "memory");
  return v;  // caller must s_waitcnt vmcnt before use
}
__device__ __forceinline__ void store_coh(float* p, float v) {
  asm volatile("global_store_dword %0, %1, off sc0 sc1" :: "v"(p), "v"(v) : "memory");
}
__device__ __forceinline__ void store_coh4(float* p, v4f v) {
  asm volatile("global_store_dwordx4 %0, %1, off sc0 sc1" :: "v"(p), "v"(v) : "memory");
}
__device__ __forceinline__ void waitvm0() {
  asm volatile("s_waitcnt vmcnt(0)" ::: "memory");
}

// ---------------------------------------------------------------------------
// Group barrier: 8 WGs per group, single counter, thread-0 spin.
// Visibility: sc0/sc1 data accesses + vmcnt(0) before arrival.
// ---------------------------------------------------------------------------
__device__ __forceinline__ void group_barrier(int* cnt, int grp, int target, int tid) {
  waitvm0();                // this wave's sc1 stores are at LLC
  __syncthreads();          // all waves drained
  if (tid == 0) {
    int* c = cnt + grp * 16;
    __hip_atomic_fetch_add(c, 1, __ATOMIC_RELAXED, __HIP_MEMORY_SCOPE_AGENT);
    while (__hip_atomic_load(c, __ATOMIC_RELAXED, __HIP_MEMORY_SCOPE_AGENT) < target)
      __builtin_amdgcn_s_sleep(1);
  }
  __syncthreads();
}

// ---------------------------------------------------------------------------
// One GRU phase. WG tile: 4 rows x 32 cols. Thread: kq=tid&7 (K eighth),
// row=(tid>>3)&3, col=tid>>5. Per-wave weight loads: 16 distinct addrs
// (8kq x 2col) x 4-row broadcast. x staged in LDS with 65-word sub-row
// swizzle (IDX) so the kq-strided reads spread across banks.
// ---------------------------------------------------------------------------
template <int NCHUNK>
__device__ void gru_phase(
    const float* __restrict__ xc0, const float* __restrict__ xc1,
    const float* __restrict__ xc2, const float* __restrict__ xc3,
    const float* __restrict__ wih, int wih_stride,
    const float* __restrict__ whh,
    const float* __restrict__ zadd,   // [B][768] precomputed z@W_z.T + bih, or null
    const float* __restrict__ bih,    // used when zadd == null
    const float* __restrict__ bhh,
    float* __restrict__ out0, float* __restrict__ out1,
    float* smem, int row0, int col0, int tid)
{
  const float* xc[4] = {xc0, xc1, xc2, xc3};
  // ---- stage x: NCHUNK chunks x 4 rows x 256 floats; 1 float4/thread ----
  v4f stg;
  int sc = 0, srr = 0, sk4 = 0;
  const int nldv = NCHUNK * 256;
  if (tid < nldv) {
    sc  = tid >> 8;
    const int r = tid & 255;
    srr = r >> 6;
    sk4 = (r & 63) << 2;
    stg = load_coh4(xc[sc] + (size_t)(row0 + srr) * H + sk4);
  }
  __syncthreads();   // previous phase done with LDS
  waitvm0();
  if (tid < nldv) {
    const int sw = (sk4 >> 6) * 65 + (sk4 & 63);   // IDX swizzle
    *reinterpret_cast<v4f*>(smem + sc * 1040 + srr * 260 + sw) = stg;
  }
  __syncthreads();

  const int kq    = tid & 7;
  const int row_l = (tid >> 3) & 3;
  const int col_l = tid >> 5;          // 0..31
  const int col   = col0 + col_l;

  const int klen   = NCHUNK * 32;      // K/8 per thread
  const int kstart = kq * klen;
  const int c      = kstart >> 8;      // chunk (never crossed: klen <= 128)
  const int koff   = kstart & 255;
  const bool is_ih = (c < NCHUNK - 1);

  const float* wb;
  int wstr;
  if (is_ih) { wstr = wih_stride; wb = wih + (size_t)col * wstr + (c * 256 + koff); }
  else       { wstr = 256;        wb = whh + (size_t)col * 256 + koff; }
  const float* wR = wb;
  const float* wZ = wb + (size_t)256 * wstr;
  const float* wN = wb + (size_t)512 * wstr;
  const float* xrow = smem + c * 1040 + row_l * 260;

  float aR = 0.f, aZ = 0.f, aN = 0.f;
  const int nkb = klen >> 6;           // 0 (klen=64 handled below) or 2
#pragma unroll
  for (int kb = 0; kb < (klen == 64 ? 1 : 2); ++kb) {
    const int kof2 = koff + kb * 64;
    const float* xb = xrow + (kof2 >> 6) * 65;
    const float* wRb = wR + kb * 64;
    const float* wZb = wZ + kb * 64;
    const float* wNb = wN + kb * 64;
#pragma unroll 8
    for (int k = 0; k < 64; k += 4) {
      v4f xv = *reinterpret_cast<const v4f*>(xb + k);
      v4f vR = *reinterpret_cast<const v4f*>(wRb + k);
      v4f vZ = *reinterpret_cast<const v4f*>(wZb + k);
      v4f vN = *reinterpret_cast<const v4f*>(wNb + k);
      aR += xv.x * vR.x; aR += xv.y * vR.y; aR += xv.z * vR.z; aR += xv.w * vR.w;
      aZ += xv.x * vZ.x; aZ += xv.y * vZ.y; aZ += xv.z * vZ.z; aZ += xv.w * vZ.w;
      aN += xv.x * vN.x; aN += xv.y * vN.y; aN += xv.z * vN.z; aN += xv.w * vN.w;
    }
  }
  (void)nkb;
  float aNi = is_ih ? aN : 0.f;
  float aNh = is_ih ? 0.f : aN;
  // reduce over the 8 kq lanes
#pragma unroll
  for (int m = 1; m <= 4; m <<= 1) {
    aR  += __shfl_xor(aR, m);
    aZ  += __shfl_xor(aZ, m);
    aNi += __shfl_xor(aNi, m);
    aNh += __shfl_xor(aNh, m);
  }
  if (kq == 0) {
    float bR, bZ, bN;
    if (zadd) {
      const float* zp = zadd + (size_t)(row0 + row_l) * G3;
      bR = zp[col]; bZ = zp[256 + col]; bN = zp[512 + col];
    } else {
      bR = bih[col]; bZ = bih[256 + col]; bN = bih[512 + col];
    }
    const float hR = bhh[col], hZ = bhh[256 + col], hN = bhh[512 + col];
    const float hold = smem[(NCHUNK - 1) * 1040 + row_l * 260 + (col >> 6) * 65 + (col & 63)];
    const float rg = sigmoidf_(aR + bR + hR);
    const float ug = sigmoidf_(aZ + bZ + hZ);
    const float ng = tanhf(aNi + bN + rg * (aNh + hN));
    const float hnew = (1.f - ug) * ng + ug * hold;
    const size_t o = (size_t)(row0 + row_l) * H + col;
    store_coh(out0 + o, hnew);
    if (out1) store_coh(out1 + o, hnew);
  }
}

// ---------------------------------------------------------------------------
// Out phase: logits=(u+h2)@ow.T+ob, write d_out slice, argmax (first-index
// ties), note[row]=emb[argmax]. One WG per row (4 of a group's 8 WGs active).
// ---------------------------------------------------------------------------
__device__ void out_phase(
    const float* __restrict__ u0i, const float* __restrict__ h2i,
    const float* __restrict__ ow, const float* __restrict__ ob,
    const float* __restrict__ embi,
    float* __restrict__ note_i, float* __restrict__ outp,
    float* smem, int* sidx, int row, bool active, int tid)
{
  if (!active) return;
  v4f a4, b4;
  if (tid < 64) {
    a4 = load_coh4(u0i + (size_t)row * H + tid * 4);
    b4 = load_coh4(h2i + (size_t)row * H + tid * 4);
  }
  __syncthreads();
  if (tid < 64) {
    waitvm0();
    *reinterpret_cast<v4f*>(smem + tid * 4) = a4 + b4;
  }
  __syncthreads();

  const int v = tid >> 2, kq = tid & 3;
  if (v < V) {
    const float* wrow = ow + (size_t)v * H + kq * 64;
    const float* xr = smem + kq * 64;
    float acc = 0.f;
#pragma unroll 8
    for (int k = 0; k < 64; k += 4) {
      v4f xv = *reinterpret_cast<const v4f*>(xr + k);
      v4f wv = *reinterpret_cast<const v4f*>(wrow + k);
      acc += xv.x * wv.x; acc += xv.y * wv.y; acc += xv.z * wv.z; acc += xv.w * wv.w;
    }
    acc += __shfl_xor(acc, 1);
    acc += __shfl_xor(acc, 2);
    if (kq == 0) {
      acc += ob[v];
      outp[v] = acc;           // d_out: normal store, visible at kernel end
      smem[256 + v] = acc;     // vals area
    }
  }
  __syncthreads();
  if (tid < 64) {
    float* vals = smem + 256;
    float bv = vals[tid]; int bi = tid;
    float c1 = vals[64 + tid];
    if (c1 > bv) { bv = c1; bi = 64 + tid; }
    if (tid < 2) { float c2 = vals[128 + tid]; if (c2 > bv) { bv = c2; bi = 128 + tid; } }
#pragma unroll
    for (int off = 32; off; off >>= 1) {
      float ov = __shfl_down(bv, off);
      int oi = __shfl_down(bi, off);
      if (ov > bv || (ov == bv && oi < bi)) { bv = ov; bi = oi; }
    }
    if (tid == 0) *sidx = bi;
  }
  __syncthreads();
  const int idx = *sidx;
  if (tid < 64) {
    v4f e = *reinterpret_cast<const v4f*>(embi + (size_t)idx * H + tid * 4);
    store_coh4(note_i + (size_t)row * H + tid * 4, e);
  }
}

// ---------------------------------------------------------------------------
// Persistent decode: 256 WGs x 1024 threads. 32 INDEPENDENT groups of 4 rows;
// group = 8 WGs (one per XCD), each owning a 32-col slice. No global barrier.
// All WGs on an XCD share the same 32-col weight slice (~2.2MB, L2-resident).
// LDS padded >80KB -> 1 WG/CU (16 waves).
// ---------------------------------------------------------------------------
__global__ __launch_bounds__(NT) void decoder_persistent(
    const float* __restrict__ g1wih, const float* __restrict__ g1whh,
    const float* __restrict__ g1bhh,
    const float* __restrict__ g2wih, const float* __restrict__ g2whh,
    const float* __restrict__ g2bhh,
    const float* __restrict__ cwih, const float* __restrict__ cwhh,
    const float* __restrict__ cbih, const float* __restrict__ cbhh,
    const float* __restrict__ outw, const float* __restrict__ outb,
    const float* __restrict__ emb,
    float* __restrict__ out, float* __restrict__ wsf)
{
  __shared__ float smem[20608];   // 82,432 B > 80 KiB -> 1 WG/CU
  __shared__ int sidx;
  __shared__ int s_tile;
  int* cnt   = reinterpret_cast<int*>(wsf) + OFF_FLAGS;
  int* xrank = reinterpret_cast<int*>(wsf) + OFF_XRANK;
  int* claim = reinterpret_cast<int*>(wsf) + OFF_CLAIM;
  float* Z1   = wsf + OFF_Z1;
  float* Z2   = wsf + OFF_Z2;
  float* g1h[2] = {wsf + OFF_G1HA, wsf + OFF_G1HB};
  float* h2b[2] = {wsf + OFF_H2A,  wsf + OFF_H2B};
  float* ctx[2] = {wsf + OFF_CTXA, wsf + OFF_CTXB};
  float* U0   = wsf + OFF_U0;
  float* U1   = wsf + OFF_U1;
  float* note = wsf + OFF_NOTE;

  const int tid = threadIdx.x;

  // ---- XCC-aware tile claim: tile = xcc*32 + group ----
  if (tid == 0) {
    int xcc;
    asm("s_getreg_b32 %0, hwreg(20, 0, 32)" : "=s"(xcc));  // HW_REG_XCC_ID
    xcc &= 7;
    int rk = __hip_atomic_fetch_add(xrank + xcc * 16, 1,
                                    __ATOMIC_RELAXED, __HIP_MEMORY_SCOPE_AGENT);
    int tile = (rk < 32) ? (xcc * 32 + rk) : ((int)blockIdx.x & 255);
    for (;;) {
      if (atomicCAS(claim + tile, 0, 1) == 0) break;   // unique claim
      tile = (tile + 1) & 255;
    }
    s_tile = tile;
  }
  __syncthreads();
  const int tile = s_tile;
  const int xs = tile >> 5;          // XCD slice -> col range (same for whole XCD)
  const int g  = tile & 31;          // group -> rows
  const int col0 = xs * 32;
  const int row0 = g * 4;
  const bool oact = (xs < 4);        // out-phase: one WG per row
  const int orow = row0 + xs;
  int ep = 0;

  for (int t = 0; t < L; ++t) {
    const int rbk = t & 1, wbk = (t + 1) & 1;
    for (int s = 0; s < 3; ++s) {
      gru_phase<2>(note + (size_t)s * BH, g1h[rbk] + (size_t)s * BH, nullptr, nullptr,
                   g1wih + (size_t)s * G3 * 512, 512, g1whh + (size_t)s * G3 * H,
                   Z1 + (size_t)s * B * G3, nullptr, g1bhh + (size_t)s * G3,
                   g1h[wbk] + (size_t)s * BH, U0 + (size_t)s * BH,
                   smem, row0, col0, tid);
    }
    group_barrier(cnt, g, (++ep) * 8, tid);
    for (int i = 0; i < 3; ++i) {
      const int j = 3 * t + i;
      const float* us0 = (0 < i ? U1 : U0) + 0 * BH;
      const float* us1 = (1 < i ? U1 : U0) + 1 * BH;
      const float* us2 = (2 < i ? U1 : U0) + 2 * BH;
      gru_phase<4>(us0, us1, us2, ctx[j & 1],
                   cwih, G3, cwhh,
                   nullptr, cbih, cbhh,
                   ctx[(j + 1) & 1], nullptr,
                   smem, row0, col0, tid);
      group_barrier(cnt, g, (++ep) * 8, tid);
      gru_phase<2>(ctx[(j + 1) & 1], h2b[rbk] + (size_t)i * BH, nullptr, nullptr,
                   g2wih + (size_t)i * G3 * 512, 512, g2whh + (size_t)i * G3 * H,
                   Z2 + (size_t)i * B * G3, nullptr, g2bhh + (size_t)i * G3,
                   h2b[wbk] + (size_t)i * BH, nullptr,
                   smem, row0, col0, tid);
      group_barrier(cnt, g, (++ep) * 8, tid);
      out_phase(U0 + (size_t)i * BH, h2b[wbk] + (size_t)i * BH,
                outw + (size_t)i * V * H, outb + (size_t)i * V, emb + (size_t)i * V * H,
                note + (size_t)i * BH,
                out + (size_t)i * B * L * V + (size_t)orow * L * V + (size_t)t * V,
                smem, &sidx, orow, oact, tid);
      group_barrier(cnt, g, (++ep) * 8, tid);
      gru_phase<2>(note + (size_t)i * BH, U0 + (size_t)i * BH, nullptr, nullptr,
                   g1wih + (size_t)1 * G3 * 512, 512, g1whh + (size_t)1 * G3 * H,
                   Z1 + (size_t)1 * B * G3, nullptr, g1bhh + (size_t)1 * G3,
                   U1 + (size_t)i * BH, nullptr,
                   smem, row0, col0, tid);
      group_barrier(cnt, g, (++ep) * 8, tid);
    }
  }
}

// ---------------------------------------------------------------------------
// Prologue kernels (outside the decode loop; cheap)
// ---------------------------------------------------------------------------
__global__ __launch_bounds__(256) void hid_kernel(
    const float* __restrict__ z, const float* __restrict__ hw,
    const float* __restrict__ hb, float* __restrict__ hidden)
{
  __shared__ float xs[32][260];
  const int tid = threadIdx.x;
  const int r = tid & 31, hc = tid >> 5;
  const int row0 = blockIdx.y * 32;
  const int col = blockIdx.x * 8 + hc;
  for (int jj = tid; jj < 32 * 64; jj += 256) {
    const int rr = jj >> 6, k4 = (jj & 63) << 2;
    *reinterpret_cast<float4*>(&xs[rr][k4]) =
        *reinterpret_cast<const float4*>(z + (size_t)(row0 + rr) * H + k4);
  }
  __syncthreads();
  float acc = 0.f;
  const float* wrow = hw + (size_t)col * H;
#pragma unroll 8
  for (int k = 0; k < 256; k += 4) {
    const float4 xv = *reinterpret_cast<const float4*>(&xs[r][k]);
    const float4 wv = *reinterpret_cast<const float4*>(wrow + k);
    acc += xv.x * wv.x; acc += xv.y * wv.y; acc += xv.z * wv.z; acc += xv.w * wv.w;
  }
  hidden[(size_t)(row0 + r) * H + col] = tanhf(acc + hb[col]);
}

__global__ __launch_bounds__(256) void zpre_kernel(
    const float* __restrict__ z, const float* __restrict__ wih,
    const float* __restrict__ bih, float* __restrict__ zout)
{
  __shared__ float xs[32][260];
  const int tid = threadIdx.x;
  const int r = tid & 31, hc = tid >> 5;
  const int row0 = blockIdx.y * 32;
  const int gr = blockIdx.x * 8 + hc;   // 0..2303
  const int s = gr / G3;
  const int gg = gr - s * G3;
  for (int jj = tid; jj < 32 * 64; jj += 256) {
    const int rr = jj >> 6, k4 = (jj & 63) << 2;
    *reinterpret_cast<float4*>(&xs[rr][k4]) =
        *reinterpret_cast<const float4*>(z + (size_t)(row0 + rr) * H + k4);
  }
  __syncthreads();
  float acc = 0.f;
  const float* wrow = wih + (size_t)gr * 512 + 256;
#pragma unroll 8
  for (int k = 0; k < 256; k += 4) {
    const float4 xv = *reinterpret_cast<const float4*>(&xs[r][k]);
    const float4 wv = *reinterpret_cast<const float4*>(wrow + k);
    acc += xv.x * wv.x; acc += xv.y * wv.y; acc += xv.z * wv.z; acc += xv.w * wv.w;
  }
  zout[((size_t)(s * B + row0 + r)) * G3 + gg] = acc + bih[gr];
}

__global__ __launch_bounds__(256) void init_copy(
    const float* __restrict__ hidden, float* __restrict__ g1h0,
    float* __restrict__ h20, float* __restrict__ ctx0)
{
  const int e = blockIdx.x * 256 + threadIdx.x;
  const float v = hidden[e];
  ctx0[e] = v;
  for (int s = 0; s < 3; ++s) {
    g1h0[(size_t)s * BH + e] = v;
    h20[(size_t)s * BH + e] = v;
  }
}

__global__ __launch_bounds__(256) void init_note(
    const float* __restrict__ emb, float* __restrict__ note)
{
  const int e = blockIdx.x * 256 + threadIdx.x;   // 0..3*B*H
  const int s = e / BH;
  const int c = e & (H - 1);
  note[e] = emb[(size_t)s * V * H + c];
}

__global__ void zero_flags(int* flags) { flags[threadIdx.x] = 0; }

extern "C" void kernel_launch(void* const* d_in, const int* in_sizes, int n_in,
                              void* d_out, int out_size, void* d_ws, size_t ws_size,
                              hipStream_t stream) {
  const float* z     = (const float*)d_in[0];
  const float* g1wih = (const float*)d_in[1];
  const float* g1whh = (const float*)d_in[2];
  const float* g1bih = (const float*)d_in[3];
  const float* g1bhh = (const float*)d_in[4];
  const float* g2wih = (const float*)d_in[5];
  const float* g2whh = (const float*)d_in[6];
  const float* g2bih = (const float*)d_in[7];
  const float* g2bhh = (const float*)d_in[8];
  const float* cwih  = (const float*)d_in[9];
  const float* cwhh  = (const float*)d_in[10];
  const float* cbih  = (const float*)d_in[11];
  const float* cbhh  = (const float*)d_in[12];
  const float* outw  = (const float*)d_in[13];
  const float* outb  = (const float*)d_in[14];
  const float* hidw  = (const float*)d_in[15];
  const float* hidb  = (const float*)d_in[16];
  const float* emb   = (const float*)d_in[17];
  float* out = (float*)d_out;
  float* wsf = (float*)d_ws;
  int* flags = (int*)d_ws;

  const dim3 blk(256);
  hid_kernel<<<dim3(32, 4), blk, 0, stream>>>(z, hidw, hidb, wsf + OFF_HID);
  zpre_kernel<<<dim3(288, 4), blk, 0, stream>>>(z, g1wih, g1bih, wsf + OFF_Z1);
  zpre_kernel<<<dim3(288, 4), blk, 0, stream>>>(z, g2wih, g2bih, wsf + OFF_Z2);
  init_copy<<<128, blk, 0, stream>>>(wsf + OFF_HID, wsf + OFF_G1HA,
                                     wsf + OFF_H2A, wsf + OFF_CTXA);
  init_note<<<384, blk, 0, stream>>>(emb, wsf + OFF_NOTE);
  zero_flags<<<1, 1024, 0, stream>>>(flags);

  decoder_persistent<<<NWG, NT, 0, stream>>>(
      g1wih, g1whh, g1bhh, g2wih, g2whh, g2bhh,
      cwih, cwhh, cbih, cbhh, outw, outb, emb, out, wsf);
}

// Round 8
// 36847.891 us; speedup vs baseline: 2.7756x; 1.0252x over previous
//
#include <hip/hip_runtime.h>
#include <math.h>

#define B 128
#define H 256
#define V 130
#define L 100
#define G3 768
#define BH (B*H)
#define NWG 256
#define NT 1024

// ---- workspace layout (4-byte words) ----
#define OFF_FLAGS 0
#define OFF_XRANK 512
#define OFF_CLAIM 640
#define OFF_HID   1024
#define OFF_Z1    (OFF_HID + BH)
#define OFF_Z2    (OFF_Z1 + 3*B*G3)
#define OFF_G1HA  (OFF_Z2 + 3*B*G3)
#define OFF_G1HB  (OFF_G1HA + 3*BH)
#define OFF_H2A   (OFF_G1HB + 3*BH)
#define OFF_H2B   (OFF_H2A + 3*BH)
#define OFF_CTXA  (OFF_H2B + 3*BH)
#define OFF_CTXB  (OFF_CTXA + BH)
#define OFF_U0    (OFF_CTXB + BH)
#define OFF_U1    (OFF_U0 + 3*BH)
#define OFF_NOTE  (OFF_U1 + 3*BH)

typedef float v4f __attribute__((ext_vector_type(4)));

__device__ __forceinline__ float sigmoidf_(float x) { return 1.0f / (1.0f + expf(-x)); }

// ---- coherence-point (LLC) accessors for cross-WG activations; weights and
// ---- biases use normal cached loads (L2-resident per XCD).
__device__ __forceinline__ v4f load_coh4(const float* p) {
  v4f v;
  asm volatile("global_load_dwordx4 %0, %1, off sc0 sc1" : "=v"(v) : "v"(p) : "memory");
  return v;  // caller must s_waitcnt vmcnt before use
}
__device__ __forceinline__ void store_coh(float* p, float v) {
  asm volatile("global_store_dword %0, %1, off sc0 sc1" :: "v"(p), "v"(v) : "memory");
}
__device__ __forceinline__ void store_coh4(float* p, v4f v) {
  asm volatile("global_store_dwordx4 %0, %1, off sc0 sc1" :: "v"(p), "v"(v) : "memory");
}
__device__ __forceinline__ void waitvm0() {
  asm volatile("s_waitcnt vmcnt(0)" ::: "memory");
}

// ---------------------------------------------------------------------------
// Group barrier: 8 WGs per group, single counter, thread-0 spin.
// ---------------------------------------------------------------------------
__device__ __forceinline__ void group_barrier(int* cnt, int grp, int target, int tid) {
  waitvm0();
  __syncthreads();
  if (tid == 0) {
    int* c = cnt + grp * 16;
    __hip_atomic_fetch_add(c, 1, __ATOMIC_RELAXED, __HIP_MEMORY_SCOPE_AGENT);
    while (__hip_atomic_load(c, __ATOMIC_RELAXED, __HIP_MEMORY_SCOPE_AGENT) < target)
      __builtin_amdgcn_s_sleep(1);
  }
  __syncthreads();
}

// ---------------------------------------------------------------------------
// One GRU phase. WG tile: 4 rows x 32 cols. Thread: kq=tid&7 (K eighth),
// row=(tid>>3)&3, col=tid>>5. Weight dot loops FULLY unrolled; with the
// 128-VGPR budget (__launch_bounds__(1024,4)) the compiler keeps many
// dwordx4 weight loads in flight -> L2/LLC latency pipelined, not serial.
// ---------------------------------------------------------------------------
template <int NCHUNK>
__device__ void gru_phase(
    const float* __restrict__ xc0, const float* __restrict__ xc1,
    const float* __restrict__ xc2, const float* __restrict__ xc3,
    const float* __restrict__ wih, int wih_stride,
    const float* __restrict__ whh,
    const float* __restrict__ zadd,   // [B][768] precomputed z@W_z.T + bih, or null
    const float* __restrict__ bih,    // used when zadd == null
    const float* __restrict__ bhh,
    float* __restrict__ out0, float* __restrict__ out1,
    float* smem, int row0, int col0, int tid)
{
  const float* xc[4] = {xc0, xc1, xc2, xc3};
  // ---- stage x: NCHUNK chunks x 4 rows x 256 floats; 1 float4/thread ----
  v4f stg;
  int sc = 0, srr = 0, sk4 = 0;
  const int nldv = NCHUNK * 256;
  if (tid < nldv) {
    sc  = tid >> 8;
    const int r = tid & 255;
    srr = r >> 6;
    sk4 = (r & 63) << 2;
    stg = load_coh4(xc[sc] + (size_t)(row0 + srr) * H + sk4);
  }
  __syncthreads();   // previous phase done with LDS
  waitvm0();
  if (tid < nldv) {
    const int sw = (sk4 >> 6) * 65 + (sk4 & 63);   // sub-row swizzle
    *reinterpret_cast<v4f*>(smem + sc * 1040 + srr * 260 + sw) = stg;
  }
  __syncthreads();

  const int kq    = tid & 7;
  const int row_l = (tid >> 3) & 3;
  const int col_l = tid >> 5;          // 0..31
  const int col   = col0 + col_l;

  const int klen   = NCHUNK * 32;      // K/8 per thread
  const int kstart = kq * klen;
  const int c      = kstart >> 8;      // chunk (never crossed: klen <= 128)
  const int koff   = kstart & 255;
  const bool is_ih = (c < NCHUNK - 1);

  const float* wb;
  int wstr;
  if (is_ih) { wstr = wih_stride; wb = wih + (size_t)col * wstr + (c * 256 + koff); }
  else       { wstr = 256;        wb = whh + (size_t)col * 256 + koff; }
  const float* wR = wb;
  const float* wZ = wb + (size_t)256 * wstr;
  const float* wN = wb + (size_t)512 * wstr;
  const float* xrow = smem + c * 1040 + row_l * 260;

  float aR = 0.f, aZ = 0.f, aN = 0.f;
#pragma unroll
  for (int kb = 0; kb < (klen == 64 ? 1 : 2); ++kb) {
    const int kof2 = koff + kb * 64;
    const float* xb = xrow + (kof2 >> 6) * 65;
    const float* wRb = wR + kb * 64;
    const float* wZb = wZ + kb * 64;
    const float* wNb = wN + kb * 64;
#pragma unroll
    for (int k = 0; k < 64; k += 4) {
      v4f xv = *reinterpret_cast<const v4f*>(xb + k);
      v4f vR = *reinterpret_cast<const v4f*>(wRb + k);
      v4f vZ = *reinterpret_cast<const v4f*>(wZb + k);
      v4f vN = *reinterpret_cast<const v4f*>(wNb + k);
      aR += xv.x * vR.x; aR += xv.y * vR.y; aR += xv.z * vR.z; aR += xv.w * vR.w;
      aZ += xv.x * vZ.x; aZ += xv.y * vZ.y; aZ += xv.z * vZ.z; aZ += xv.w * vZ.w;
      aN += xv.x * vN.x; aN += xv.y * vN.y; aN += xv.z * vN.z; aN += xv.w * vN.w;
    }
  }
  float aNi = is_ih ? aN : 0.f;
  float aNh = is_ih ? 0.f : aN;
#pragma unroll
  for (int m = 1; m <= 4; m <<= 1) {
    aR  += __shfl_xor(aR, m);
    aZ  += __shfl_xor(aZ, m);
    aNi += __shfl_xor(aNi, m);
    aNh += __shfl_xor(aNh, m);
  }
  if (kq == 0) {
    float bR, bZ, bN;
    if (zadd) {
      const float* zp = zadd + (size_t)(row0 + row_l) * G3;
      bR = zp[col]; bZ = zp[256 + col]; bN = zp[512 + col];
    } else {
      bR = bih[col]; bZ = bih[256 + col]; bN = bih[512 + col];
    }
    const float hR = bhh[col], hZ = bhh[256 + col], hN = bhh[512 + col];
    const float hold = smem[(NCHUNK - 1) * 1040 + row_l * 260 + (col >> 6) * 65 + (col & 63)];
    const float rg = sigmoidf_(aR + bR + hR);
    const float ug = sigmoidf_(aZ + bZ + hZ);
    const float ng = tanhf(aNi + bN + rg * (aNh + hN));
    const float hnew = (1.f - ug) * ng + ug * hold;
    const size_t o = (size_t)(row0 + row_l) * H + col;
    store_coh(out0 + o, hnew);
    if (out1) store_coh(out1 + o, hnew);
  }
}

// ---------------------------------------------------------------------------
// Out phase: logits=(u+h2)@ow.T+ob, store d_out slice (nt), argmax
// (first-index ties), note[row]=emb[argmax]. One WG per row.
// ---------------------------------------------------------------------------
__device__ void out_phase(
    const float* __restrict__ u0i, const float* __restrict__ h2i,
    const float* __restrict__ ow, const float* __restrict__ ob,
    const float* __restrict__ embi,
    float* __restrict__ note_i, float* __restrict__ outp,
    float* smem, int* sidx, int row, bool active, int tid)
{
  if (!active) return;
  v4f a4, b4;
  if (tid < 64) {
    a4 = load_coh4(u0i + (size_t)row * H + tid * 4);
    b4 = load_coh4(h2i + (size_t)row * H + tid * 4);
  }
  __syncthreads();
  if (tid < 64) {
    waitvm0();
    *reinterpret_cast<v4f*>(smem + tid * 4) = a4 + b4;
  }
  __syncthreads();

  const int v = tid >> 2, kq = tid & 3;
  if (v < V) {
    const float* wrow = ow + (size_t)v * H + kq * 64;
    const float* xr = smem + kq * 64;
    float acc = 0.f;
#pragma unroll
    for (int k = 0; k < 64; k += 4) {
      v4f xv = *reinterpret_cast<const v4f*>(xr + k);
      v4f wv = *reinterpret_cast<const v4f*>(wrow + k);
      acc += xv.x * wv.x; acc += xv.y * wv.y; acc += xv.z * wv.z; acc += xv.w * wv.w;
    }
    acc += __shfl_xor(acc, 1);
    acc += __shfl_xor(acc, 2);
    if (kq == 0) {
      acc += ob[v];
      store_coh(outp + v, acc);   // d_out: keep out of L2
      smem[256 + v] = acc;        // vals area
    }
  }
  __syncthreads();
  if (tid < 64) {
    float* vals = smem + 256;
    float bv = vals[tid]; int bi = tid;
    float c1 = vals[64 + tid];
    if (c1 > bv) { bv = c1; bi = 64 + tid; }
    if (tid < 2) { float c2 = vals[128 + tid]; if (c2 > bv) { bv = c2; bi = 128 + tid; } }
#pragma unroll
    for (int off = 32; off; off >>= 1) {
      float ov = __shfl_down(bv, off);
      int oi = __shfl_down(bi, off);
      if (ov > bv || (ov == bv && oi < bi)) { bv = ov; bi = oi; }
    }
    if (tid == 0) *sidx = bi;
  }
  __syncthreads();
  const int idx = *sidx;
  if (tid < 64) {
    v4f e = *reinterpret_cast<const v4f*>(embi + (size_t)idx * H + tid * 4);
    store_coh4(note_i + (size_t)row * H + tid * 4, e);
  }
}

// ---------------------------------------------------------------------------
// Persistent decode: 256 WGs x 1024 threads. 32 independent groups of 4 rows;
// group = 8 WGs (one per XCD), each owning a 32-col slice.
// LDS >80KB -> 1 WG/CU (16 waves). launch_bounds(1024,4) -> 128-VGPR cap.
// ---------------------------------------------------------------------------
__global__ __launch_bounds__(NT, 4) void decoder_persistent(
    const float* __restrict__ g1wih, const float* __restrict__ g1whh,
    const float* __restrict__ g1bhh,
    const float* __restrict__ g2wih, const float* __restrict__ g2whh,
    const float* __restrict__ g2bhh,
    const float* __restrict__ cwih, const float* __restrict__ cwhh,
    const float* __restrict__ cbih, const float* __restrict__ cbhh,
    const float* __restrict__ outw, const float* __restrict__ outb,
    const float* __restrict__ emb,
    float* __restrict__ out, float* __restrict__ wsf)
{
  __shared__ float smem[20608];   // 82,432 B > 80 KiB -> 1 WG/CU
  __shared__ int sidx;
  __shared__ int s_tile;
  int* cnt   = reinterpret_cast<int*>(wsf) + OFF_FLAGS;
  int* xrank = reinterpret_cast<int*>(wsf) + OFF_XRANK;
  int* claim = reinterpret_cast<int*>(wsf) + OFF_CLAIM;
  float* Z1   = wsf + OFF_Z1;
  float* Z2   = wsf + OFF_Z2;
  float* g1h[2] = {wsf + OFF_G1HA, wsf + OFF_G1HB};
  float* h2b[2] = {wsf + OFF_H2A,  wsf + OFF_H2B};
  float* ctx[2] = {wsf + OFF_CTXA, wsf + OFF_CTXB};
  float* U0   = wsf + OFF_U0;
  float* U1   = wsf + OFF_U1;
  float* note = wsf + OFF_NOTE;

  const int tid = threadIdx.x;

  // ---- XCC-aware tile claim: tile = xcc*32 + rank ----
  if (tid == 0) {
    int xcc;
    asm("s_getreg_b32 %0, hwreg(20, 0, 32)" : "=s"(xcc));  // HW_REG_XCC_ID
    xcc &= 7;
    int rk = __hip_atomic_fetch_add(xrank + xcc * 16, 1,
                                    __ATOMIC_RELAXED, __HIP_MEMORY_SCOPE_AGENT);
    int tile = (rk < 32) ? (xcc * 32 + rk) : ((int)blockIdx.x & 255);
    for (;;) {
      if (atomicCAS(claim + tile, 0, 1) == 0) break;
      tile = (tile + 1) & 255;
    }
    s_tile = tile;
  }
  __syncthreads();
  const int tile = s_tile;
  const int xs = tile >> 5;          // XCD slice -> col range
  const int g  = tile & 31;          // group -> rows
  const int col0 = xs * 32;
  const int row0 = g * 4;
  const bool oact = (xs < 4);
  const int orow = row0 + xs;
  int ep = 0;

  for (int t = 0; t < L; ++t) {
    const int rbk = t & 1, wbk = (t + 1) & 1;
    for (int s = 0; s < 3; ++s) {
      gru_phase<2>(note + (size_t)s * BH, g1h[rbk] + (size_t)s * BH, nullptr, nullptr,
                   g1wih + (size_t)s * G3 * 512, 512, g1whh + (size_t)s * G3 * H,
                   Z1 + (size_t)s * B * G3, nullptr, g1bhh + (size_t)s * G3,
                   g1h[wbk] + (size_t)s * BH, U0 + (size_t)s * BH,
                   smem, row0, col0, tid);
    }
    group_barrier(cnt, g, (++ep) * 8, tid);
    for (int i = 0; i < 3; ++i) {
      const int j = 3 * t + i;
      const float* us0 = (0 < i ? U1 : U0) + 0 * BH;
      const float* us1 = (1 < i ? U1 : U0) + 1 * BH;
      const float* us2 = (2 < i ? U1 : U0) + 2 * BH;
      gru_phase<4>(us0, us1, us2, ctx[j & 1],
                   cwih, G3, cwhh,
                   nullptr, cbih, cbhh,
                   ctx[(j + 1) & 1], nullptr,
                   smem, row0, col0, tid);
      group_barrier(cnt, g, (++ep) * 8, tid);
      gru_phase<2>(ctx[(j + 1) & 1], h2b[rbk] + (size_t)i * BH, nullptr, nullptr,
                   g2wih + (size_t)i * G3 * 512, 512, g2whh + (size_t)i * G3 * H,
                   Z2 + (size_t)i * B * G3, nullptr, g2bhh + (size_t)i * G3,
                   h2b[wbk] + (size_t)i * BH, nullptr,
                   smem, row0, col0, tid);
      group_barrier(cnt, g, (++ep) * 8, tid);
      out_phase(U0 + (size_t)i * BH, h2b[wbk] + (size_t)i * BH,
                outw + (size_t)i * V * H, outb + (size_t)i * V, emb + (size_t)i * V * H,
                note + (size_t)i * BH,
                out + (size_t)i * B * L * V + (size_t)orow * L * V + (size_t)t * V,
                smem, &sidx, orow, oact, tid);
      group_barrier(cnt, g, (++ep) * 8, tid);
      gru_phase<2>(note + (size_t)i * BH, U0 + (size_t)i * BH, nullptr, nullptr,
                   g1wih + (size_t)1 * G3 * 512, 512, g1whh + (size_t)1 * G3 * H,
                   Z1 + (size_t)1 * B * G3, nullptr, g1bhh + (size_t)1 * G3,
                   U1 + (size_t)i * BH, nullptr,
                   smem, row0, col0, tid);
      group_barrier(cnt, g, (++ep) * 8, tid);
    }
  }
}

// ---------------------------------------------------------------------------
// Prologue kernels (outside the decode loop; cheap)
// ---------------------------------------------------------------------------
__global__ __launch_bounds__(256) void hid_kernel(
    const float* __restrict__ z, const float* __restrict__ hw,
    const float* __restrict__ hb, float* __restrict__ hidden)
{
  __shared__ float xs[32][260];
  const int tid = threadIdx.x;
  const int r = tid & 31, hc = tid >> 5;
  const int row0 = blockIdx.y * 32;
  const int col = blockIdx.x * 8 + hc;
  for (int jj = tid; jj < 32 * 64; jj += 256) {
    const int rr = jj >> 6, k4 = (jj & 63) << 2;
    *reinterpret_cast<float4*>(&xs[rr][k4]) =
        *reinterpret_cast<const float4*>(z + (size_t)(row0 + rr) * H + k4);
  }
  __syncthreads();
  float acc = 0.f;
  const float* wrow = hw + (size_t)col * H;
#pragma unroll 8
  for (int k = 0; k < 256; k += 4) {
    const float4 xv = *reinterpret_cast<const float4*>(&xs[r][k]);
    const float4 wv = *reinterpret_cast<const float4*>(wrow + k);
    acc += xv.x * wv.x; acc += xv.y * wv.y; acc += xv.z * wv.z; acc += xv.w * wv.w;
  }
  hidden[(size_t)(row0 + r) * H + col] = tanhf(acc + hb[col]);
}

__global__ __launch_bounds__(256) void zpre_kernel(
    const float* __restrict__ z, const float* __restrict__ wih,
    const float* __restrict__ bih, float* __restrict__ zout)
{
  __shared__ float xs[32][260];
  const int tid = threadIdx.x;
  const int r = tid & 31, hc = tid >> 5;
  const int row0 = blockIdx.y * 32;
  const int gr = blockIdx.x * 8 + hc;   // 0..2303
  const int s = gr / G3;
  const int gg = gr - s * G3;
  for (int jj = tid; jj < 32 * 64; jj += 256) {
    const int rr = jj >> 6, k4 = (jj & 63) << 2;
    *reinterpret_cast<float4*>(&xs[rr][k4]) =
        *reinterpret_cast<const float4*>(z + (size_t)(row0 + rr) * H + k4);
  }
  __syncthreads();
  float acc = 0.f;
  const float* wrow = wih + (size_t)gr * 512 + 256;
#pragma unroll 8
  for (int k = 0; k < 256; k += 4) {
    const float4 xv = *reinterpret_cast<const float4*>(&xs[r][k]);
    const float4 wv = *reinterpret_cast<const float4*>(wrow + k);
    acc += xv.x * wv.x; acc += xv.y * wv.y; acc += xv.z * wv.z; acc += xv.w * wv.w;
  }
  zout[((size_t)(s * B + row0 + r)) * G3 + gg] = acc + bih[gr];
}

__global__ __launch_bounds__(256) void init_copy(
    const float* __restrict__ hidden, float* __restrict__ g1h0,
    float* __restrict__ h20, float* __restrict__ ctx0)
{
  const int e = blockIdx.x * 256 + threadIdx.x;
  const float v = hidden[e];
  ctx0[e] = v;
  for (int s = 0; s < 3; ++s) {
    g1h0[(size_t)s * BH + e] = v;
    h20[(size_t)s * BH + e] = v;
  }
}

__global__ __launch_bounds__(256) void init_note(
    const float* __restrict__ emb, float* __restrict__ note)
{
  const int e = blockIdx.x * 256 + threadIdx.x;   // 0..3*B*H
  const int s = e / BH;
  const int c = e & (H - 1);
  note[e] = emb[(size_t)s * V * H + c];
}

__global__ void zero_flags(int* flags) { flags[threadIdx.x] = 0; }

extern "C" void kernel_launch(void* const* d_in, const int* in_sizes, int n_in,
                              void* d_out, int out_size, void* d_ws, size_t ws_size,
                              hipStream_t stream) {
  const float* z     = (const float*)d_in[0];
  const float* g1wih = (const float*)d_in[1];
  const float* g1whh = (const float*)d_in[2];
  const float* g1bih = (const float*)d_in[3];
  const float* g1bhh = (const float*)d_in[4];
  const float* g2wih = (const float*)d_in[5];
  const float* g2whh = (const float*)d_in[6];
  const float* g2bih = (const float*)d_in[7];
  const float* g2bhh = (const float*)d_in[8];
  const float* cwih  = (const float*)d_in[9];
  const float* cwhh  = (const float*)d_in[10];
  const float* cbih  = (const float*)d_in[11];
  const float* cbhh  = (const float*)d_in[12];
  const float* outw  = (const float*)d_in[13];
  const float* outb  = (const float*)d_in[14];
  const float* hidw  = (const float*)d_in[15];
  const float* hidb  = (const float*)d_in[16];
  const float* emb   = (const float*)d_in[17];
  float* out = (float*)d_out;
  float* wsf = (float*)d_ws;
  int* flags = (int*)d_ws;

  const dim3 blk(256);
  hid_kernel<<<dim3(32, 4), blk, 0, stream>>>(z, hidw, hidb, wsf + OFF_HID);
  zpre_kernel<<<dim3(288, 4), blk, 0, stream>>>(z, g1wih, g1bih, wsf + OFF_Z1);
  zpre_kernel<<<dim3(288, 4), blk, 0, stream>>>(z, g2wih, g2bih, wsf + OFF_Z2);
  init_copy<<<128, blk, 0, stream>>>(wsf + OFF_HID, wsf + OFF_G1HA,
                                     wsf + OFF_H2A, wsf + OFF_CTXA);
  init_note<<<384, blk, 0, stream>>>(emb, wsf + OFF_NOTE);
  zero_flags<<<1, 1024, 0, stream>>>(flags);

  decoder_persistent<<<NWG, NT, 0, stream>>>(
      g1wih, g1whh, g1bhh, g2wih, g2whh, g2bhh,
      cwih, cwhh, cbih, cbhh, outw, outb, emb, out, wsf);
}